// Round 9
// baseline (3304.525 us; speedup 1.0000x reference)
//
#include <hip/hip_runtime.h>
#include <math.h>

#define Hd 512
#define Bd 64
#define Pd 32
#define Rd 4
#define Wd 64

typedef _Float16 h2v __attribute__((ext_vector_type(2)));

__device__ __forceinline__ float tanh_fast(float x) {
    float e = __expf(x + x);
    return 1.f - __fdividef(2.f, 1.f + e);
}

__device__ __forceinline__ float d2(unsigned a, unsigned b, float c) {
    return __builtin_amdgcn_fdot2(__builtin_bit_cast(h2v, a),
                                  __builtin_bit_cast(h2v, b), c, false);
}

__device__ __forceinline__ unsigned pk(float a, float b) {
    h2v p; p.x = (_Float16)a; p.y = (_Float16)b;
    return __builtin_bit_cast(unsigned, p);
}

// ---- build WAp = fp16-packed [W_a | lin_w^T] (256 h2 x 1024) + Wtp (256 h2 x 512) ----
__global__ __launch_bounds__(256) void k_prep(const float* __restrict__ Wa,
                                              const float* __restrict__ lin_w,
                                              const float* __restrict__ Wt,
                                              unsigned* __restrict__ WAp,
                                              unsigned* __restrict__ Wtp) {
    __shared__ unsigned tile[32][33];
    int bx = blockIdx.x, by = blockIdx.y;
    int lane = threadIdx.x & 31, ty = threadIdx.x >> 5;
    for (int k = 0; k < 32; k += 8) {
        int h2 = by * 32 + ty + k, c = bx * 32 + lane;
        WAp[(size_t)h2 * 1024 + c] = pk(Wa[(size_t)(2 * h2) * Hd + c],
                                        Wa[(size_t)(2 * h2 + 1) * Hd + c]);
        Wtp[(size_t)h2 * 512 + c]  = pk(Wt[(size_t)(2 * h2) * Hd + c],
                                        Wt[(size_t)(2 * h2 + 1) * Hd + c]);
    }
    for (int k = 0; k < 32; k += 8) {
        int c_src = bx * 32 + ty + k, h2 = by * 32 + lane;
        float2 v = *(const float2*)&lin_w[(size_t)c_src * Hd + 2 * h2];
        tile[ty + k][lane] = pk(v.x, v.y);
    }
    __syncthreads();
    for (int k = 0; k < 32; k += 8) {
        int h2o = by * 32 + ty + k, co = bx * 32 + lane;
        WAp[(size_t)h2o * 1024 + 512 + co] = tile[lane][ty + k];
    }
}

// ---------------- Wctx[b,p,k] = sum_h ctx[b,p,h] * Wc[h,k]  (32 rows/block) ----------------
__global__ __launch_bounds__(256) void k_wctx(const float* __restrict__ ctx_pbh,
                                              const float* __restrict__ Wc,
                                              float* __restrict__ Wctx) {
    __shared__ float As[32][Hd];
    int r0 = blockIdx.x * 32;
    int tid = threadIdx.x;
    for (int rr = 0; rr < 32; ++rr) {
        int bp = r0 + rr;
        int b = bp >> 5, p = bp & 31;
        const float* src = ctx_pbh + ((size_t)p * Bd + b) * Hd;
        for (int h = tid; h < Hd; h += 256) As[rr][h] = src[h];
    }
    __syncthreads();
    int c0 = tid, c1 = tid + 256;
    float acc0[32], acc1[32];
    #pragma unroll
    for (int rr = 0; rr < 32; ++rr) { acc0[rr] = 0.f; acc1[rr] = 0.f; }
    for (int h = 0; h < Hd; ++h) {
        float w0 = Wc[(size_t)h * Hd + c0], w1 = Wc[(size_t)h * Hd + c1];
        #pragma unroll
        for (int rr = 0; rr < 32; ++rr) {
            float a = As[rr][h];
            acc0[rr] += a * w0;
            acc1[rr] += a * w1;
        }
    }
    for (int rr = 0; rr < 32; ++rr) {
        Wctx[(size_t)(r0 + rr) * Hd + c0] = acc0[rr];
        Wctx[(size_t)(r0 + rr) * Hd + c1] = acc1[rr];
    }
}

// ---------------- rwh[t*256+row][c] = fp16(sum_h resp * Wt), dot2 path ----------------
__global__ __launch_bounds__(512) void k_rw(const float* __restrict__ resp,
                                            const unsigned* __restrict__ Wtp,
                                            unsigned short* __restrict__ rwh) {
    __shared__ unsigned As[32 * 256];
    int gr0 = blockIdx.x * 32, tid = threadIdx.x;
    for (int i = tid; i < 32 * 256; i += 512) {
        int rr = i >> 8, h2 = i & 255;
        int gr = gr0 + rr;
        int t = gr >> 8, row = gr & 255, r = row >> 6, bb = row & 63;
        float2 v = *(const float2*)(resp + (((size_t)(r * Wd + t)) * Bd + bb) * Hd + (h2 << 1));
        As[i] = pk(v.x, v.y);
    }
    __syncthreads();
    float acc[32];
    #pragma unroll
    for (int rr = 0; rr < 32; ++rr) acc[rr] = 0.f;
    const int c = tid;
    #pragma unroll 1
    for (int h2 = 0; h2 < 256; h2 += 4) {
        unsigned w0 = Wtp[((h2 + 0) << 9) + c];
        unsigned w1 = Wtp[((h2 + 1) << 9) + c];
        unsigned w2 = Wtp[((h2 + 2) << 9) + c];
        unsigned w3 = Wtp[((h2 + 3) << 9) + c];
        #pragma unroll
        for (int rr = 0; rr < 32; ++rr) {
            uint4 a4 = *(const uint4*)&As[(rr << 8) + h2];
            float s = acc[rr];
            s = d2(a4.x, w0, s); s = d2(a4.y, w1, s);
            s = d2(a4.z, w2, s); s = d2(a4.w, w3, s);
            acc[rr] = s;
        }
    }
    for (int rr = 0; rr < 32; ++rr)
        rwh[((size_t)(gr0 + rr) << 9) + c] =
            __builtin_bit_cast(unsigned short, (_Float16)acc[rr]);
}

// issue 16 uint2 loads of sub-chunk S (16 h2) at column offset OFF into BUF
#define ISSUE_SUB(BUF, OFF, S)                                              \
    _Pragma("unroll")                                                       \
    for (int jj = 0; jj < 16; ++jj)                                         \
        BUF[jj] = *(const uint2*)(wbase + (OFF) + (size_t)(((S) << 4) + jj) * 1024);

// consume BUF (sub-chunk S) against attenH, accumulate into ACC
#define DOT_SUB(BUF, S, ACC) do {                                           \
    const uint4* ap_ = attenH4 + (q << 4) + ((S) << 2);                     \
    uint4 A0 = ap_[0], A1 = ap_[1], A2 = ap_[2], A3 = ap_[3];               \
    ACC.x = d2(A0.x, BUF[0].x,  ACC.x); ACC.y = d2(A0.x, BUF[0].y,  ACC.y); \
    ACC.x = d2(A0.y, BUF[1].x,  ACC.x); ACC.y = d2(A0.y, BUF[1].y,  ACC.y); \
    ACC.x = d2(A0.z, BUF[2].x,  ACC.x); ACC.y = d2(A0.z, BUF[2].y,  ACC.y); \
    ACC.x = d2(A0.w, BUF[3].x,  ACC.x); ACC.y = d2(A0.w, BUF[3].y,  ACC.y); \
    ACC.x = d2(A1.x, BUF[4].x,  ACC.x); ACC.y = d2(A1.x, BUF[4].y,  ACC.y); \
    ACC.x = d2(A1.y, BUF[5].x,  ACC.x); ACC.y = d2(A1.y, BUF[5].y,  ACC.y); \
    ACC.x = d2(A1.z, BUF[6].x,  ACC.x); ACC.y = d2(A1.z, BUF[6].y,  ACC.y); \
    ACC.x = d2(A1.w, BUF[7].x,  ACC.x); ACC.y = d2(A1.w, BUF[7].y,  ACC.y); \
    ACC.x = d2(A2.x, BUF[8].x,  ACC.x); ACC.y = d2(A2.x, BUF[8].y,  ACC.y); \
    ACC.x = d2(A2.y, BUF[9].x,  ACC.x); ACC.y = d2(A2.y, BUF[9].y,  ACC.y); \
    ACC.x = d2(A2.z, BUF[10].x, ACC.x); ACC.y = d2(A2.z, BUF[10].y, ACC.y); \
    ACC.x = d2(A2.w, BUF[11].x, ACC.x); ACC.y = d2(A2.w, BUF[11].y, ACC.y); \
    ACC.x = d2(A3.x, BUF[12].x, ACC.x); ACC.y = d2(A3.x, BUF[12].y, ACC.y); \
    ACC.x = d2(A3.y, BUF[13].x, ACC.x); ACC.y = d2(A3.y, BUF[13].y, ACC.y); \
    ACC.x = d2(A3.z, BUF[14].x, ACC.x); ACC.y = d2(A3.z, BUF[14].y, ACC.y); \
    ACC.x = d2(A3.w, BUF[15].x, ACC.x); ACC.y = d2(A3.w, BUF[15].y, ACC.y); \
} while (0)

// ---------------- persistent scan: 256 blocks (one per (r,b)), 1024 threads ----------------
// Software-pipelined, full-width streaming, barrier-only sync (4/step):
//  P1: dot head (ping-pong prefetched) + issue tail s0/s1; atomicAdd -> sW head.
//  P2: tanh-score (tail s0/s1 fill underneath).
//  P3: dot tail + issue next-step head s0/s1, softmax stats (m,sum) interleaved.
//  P4: ctx-reduce + tanh(lw) + atten pack || rw(t+1) preload (next head fills underneath).
__global__ __launch_bounds__(1024, 4) void k_scan(
    const float* __restrict__ ctx,      // (P,B,H)
    const unsigned short* __restrict__ rwh, // (W*256, H) fp16
    const unsigned* __restrict__ WAp,   // (H/2, 1024) half2 pairs along h
    const float* __restrict__ Wctx,     // (B*P, H)
    const float* __restrict__ walpha,   // (H)
    const float* __restrict__ hidden,   // (R,B,H)
    const float* __restrict__ lin_p,    // (H,H)
    const float* __restrict__ lin_x,    // (H,H)
    float* __restrict__ out_resp,       // (R,B,H)
    float* __restrict__ out_alpha)      // (R,W,B,P)
{
    extern __shared__ float dynS[];
    float* sCtx   = dynS;                           // [32][512] 64 KB (persistent)
    float* sWctx  = dynS + 16384;                   // [32][512] 64 KB (persistent; epilogue scratch)
    float* sW     = dynS + 32768;                   // [1024]     4 KB
    float* sWal   = dynS + 33792;                   // [512]      2 KB
    float* sAtten = dynS + 34304;                   // [512]      2 KB
    float* scS    = dynS + 34816;                   // [32]
    unsigned* attenH = (unsigned*)(dynS + 34848);   // [256] half2 atten (16B aligned)
    const uint4* attenH4 = (const uint4*)attenH;

    const int bid = blockIdx.x;
    const int r_ = bid >> 6, b_ = bid & 63;
    const int tid = threadIdx.x;
    const unsigned* rwU = (const unsigned*)rwh;

    // ---- identities ----
    const int q  = tid >> 8;                  // h2-quarter 0..3 (64 h2)
    const int cp = tid & 255;                 // col-pair within 512-col chunk
    const unsigned* __restrict__ wbase = WAp + ((size_t)(q << 6)) * 1024 + 2 * cp;
    const int pB = tid >> 5, hc = tid & 31;   // score: 32 threads per p

    // ---- preamble ----
    for (int i = tid; i < 4096; i += 1024) {
        int p = i >> 7, h4 = (i & 127) << 2;
        *(float4*)&sCtx[(p << 9) + h4] =
            *(const float4*)&ctx[((size_t)(p * Bd + b_)) * Hd + h4];
        *(float4*)&sWctx[(p << 9) + h4] =
            *(const float4*)&Wctx[((size_t)(b_ * Pd + p)) * Hd + h4];
    }
    if (tid < Hd) sWal[tid] = walpha[tid];
    if (tid < 256) {
        attenH[tid] = 0u;
        unsigned u = rwU[((size_t)(r_ * 64 + b_)) * 256 + tid];
        h2v hp = __builtin_bit_cast(h2v, u);
        sW[2 * tid]     = (float)hp.x;
        sW[2 * tid + 1] = (float)hp.y;
    }
    uint2 bA[16], bB[16];
    ISSUE_SUB(bA, 0, 0);          // prime head s0
    ISSUE_SUB(bB, 0, 1);          // prime head s1
    __syncthreads();

    float m = 0.f, inv = 0.f;

    for (int t = 0; t < Wd; ++t) {
        // ================= P1: head GEMV (cols 0-511) =================
        {
            if (tid < 512) sW[512 + tid] = 0.f;   // zero tail for P3 atomics
            float2 acc = make_float2(0.f, 0.f);
            DOT_SUB(bA, 0, acc);  ISSUE_SUB(bA, 0, 2);
            DOT_SUB(bB, 1, acc);  ISSUE_SUB(bB, 0, 3);
            DOT_SUB(bA, 2, acc);  ISSUE_SUB(bA, 512, 0);   // tail s0 (fills under P2)
            DOT_SUB(bB, 3, acc);  ISSUE_SUB(bB, 512, 1);   // tail s1
            atomicAdd(&sW[2 * cp],     acc.x);
            atomicAdd(&sW[2 * cp + 1], acc.y);
        }
        __syncthreads();   // B1: sW head complete (rw + GEMV)

        // ================= P2: tanh-score from head w (tail s0/s1 filling) =================
        {
            const float* __restrict__ wrow = sWctx + (pB << 9);
            float sc = 0.f;
            #pragma unroll
            for (int k = 0; k < 4; ++k) {
                int h4 = (k << 7) + (hc << 2);
                float4 wc = *(const float4*)&wrow[h4];
                float4 wl = *(const float4*)&sWal[h4];
                float4 v  = *(const float4*)&sW[h4];
                sc += tanh_fast(wc.x + v.x) * wl.x + tanh_fast(wc.y + v.y) * wl.y
                    + tanh_fast(wc.z + v.z) * wl.z + tanh_fast(wc.w + v.w) * wl.w;
            }
            #pragma unroll
            for (int off = 16; off; off >>= 1) sc += __shfl_down(sc, off, 32);
            if (hc == 0) scS[pB] = sc;
        }
        __syncthreads();   // B2: scores complete

        // ================= P3: tail GEMV + softmax stats =================
        {
            float2 acc = make_float2(0.f, 0.f);
            DOT_SUB(bA, 0, acc);  ISSUE_SUB(bA, 512, 2);
            DOT_SUB(bB, 1, acc);  ISSUE_SUB(bB, 512, 3);
            // softmax stats while tail s2/s3 fill (no sv[] array -> low VGPR)
            float mm = scS[0];
            #pragma unroll
            for (int p = 1; p < Pd; ++p) mm = fmaxf(mm, scS[p]);
            float sum = 0.f;
            #pragma unroll
            for (int p = 0; p < Pd; ++p) sum += __expf(scS[p] - mm);
            m = mm;
            inv = __fdividef(1.f, sum);
            DOT_SUB(bA, 2, acc);  ISSUE_SUB(bA, 0, 0);     // next-step head s0 (fills under P4)
            DOT_SUB(bB, 3, acc);  ISSUE_SUB(bB, 0, 1);     // next-step head s1
            atomicAdd(&sW[512 + 2 * cp],     acc.x);
            atomicAdd(&sW[512 + 2 * cp + 1], acc.y);
        }
        __syncthreads();   // B3: sW tail (lw) complete

        // ================= P4: update || rw(t+1) preload (next head filling) =================
        if (tid < 512) {
            float a = 0.f;
            #pragma unroll 8
            for (int p = 0; p < Pd; ++p)
                a += __expf(scS[p] - m) * sCtx[(p << 9) + tid];
            a = a * inv + tanh_fast(sW[512 + tid]);
            sAtten[tid] = a;
            if (tid < Pd)
                out_alpha[(((size_t)r_ * Wd + t) * Bd + b_) * Pd + tid] =
                    __expf(scS[tid] - m) * inv;
            float an = __shfl_down(a, 1, 64);
            if (!(tid & 1)) attenH[tid >> 1] = pk(a, an);
        } else {
            const int tp = tid - 512;
            if (tp < 256 && t < Wd - 1) {
                unsigned u = rwU[((size_t)((t + 1) * 256 + r_ * 64 + b_)) * 256 + tp];
                h2v hp = __builtin_bit_cast(h2v, u);
                sW[2 * tp]     = (float)hp.x;
                sW[2 * tp + 1] = (float)hp.y;
            }
        }
        __syncthreads();   // B4: atten + next sW head ready
    }

    // ---- epilogue: resp_c = tanh(atten@lin_p^T + hidden@lin_x^T) ----
    if (tid < Hd) sWctx[tid] = hidden[((size_t)(r_ * Bd + b_)) * Hd + tid];
    __syncthreads();
    {
        const int half = tid >> 9;
        const int c = tid & 511;
        const int hb = half << 8;
        const float* __restrict__ lp = lin_p + (size_t)c * Hd + hb;
        const float* __restrict__ lx = lin_x + (size_t)c * Hd + hb;
        float f = 0.f;
        #pragma unroll 2
        for (int h = 0; h < 256; h += 4) {
            float4 lpv = *(const float4*)(lp + h);
            float4 lxv = *(const float4*)(lx + h);
            float4 aa  = *(const float4*)&sAtten[hb + h];
            float4 hh  = *(const float4*)&sWctx[hb + h];
            f += aa.x*lpv.x + aa.y*lpv.y + aa.z*lpv.z + aa.w*lpv.w
               + hh.x*lxv.x + hh.y*lxv.y + hh.z*lxv.z + hh.w*lxv.w;
        }
        sWctx[1024 + (half << 9) + c] = f;
    }
    __syncthreads();
    if (tid < Hd) {
        float f = sWctx[1024 + tid] + sWctx[1536 + tid];
        out_resp[((size_t)(r_ * Bd + b_)) * Hd + tid] = tanh_fast(f);
    }
}

extern "C" void kernel_launch(void* const* d_in, const int* in_sizes, int n_in,
                              void* d_out, int out_size, void* d_ws, size_t ws_size,
                              hipStream_t stream) {
    const float* ctx    = (const float*)d_in[0];  // (P,B,H)
    const float* resp   = (const float*)d_in[1];  // (R,W,B,H)
    const float* hidden = (const float*)d_in[2];  // (R,B,H)
    const float* Wc     = (const float*)d_in[3];
    const float* Wt     = (const float*)d_in[4];
    const float* Wa     = (const float*)d_in[5];
    const float* Walpha = (const float*)d_in[6];  // (H,1)
    const float* lin_w  = (const float*)d_in[7];
    const float* lin_p  = (const float*)d_in[8];
    const float* lin_x  = (const float*)d_in[9];

    float* out = (float*)d_out;
    float* resp_c_out = out;                       // R*B*H
    float* alpha_out  = out + Rd * Bd * Hd;        // R*W*B*P

    float* ws = (float*)d_ws;
    unsigned* WAp = (unsigned*)ws;                          //   262144 u32 (1 MB)
    unsigned* Wtp = (unsigned*)(ws + 262144);               //   131072 u32 (0.5 MB)
    float* Wctx   = ws + 393216;                            //  1048576 f32 (4 MB)
    unsigned short* rwh = (unsigned short*)(ws + 1441792);  //  8388608 u16 (16 MB)

    k_prep<<<dim3(16, 8), 256, 0, stream>>>(Wa, lin_w, Wt, WAp, Wtp);
    k_wctx<<<64, 256, 0, stream>>>(ctx, Wc, Wctx);
    k_rw<<<512, 512, 0, stream>>>(resp, Wtp, rwh);

    const int dyn_lds = 140416;                    // 35104 floats (~137 KB)
    static bool s_attr = false;
    if (!s_attr) {
        hipFuncSetAttribute((const void*)k_scan,
                            hipFuncAttributeMaxDynamicSharedMemorySize, dyn_lds);
        s_attr = true;
    }
    k_scan<<<256, 1024, dyn_lds, stream>>>(ctx, rwh, WAp, Wctx, Walpha, hidden,
                                           lin_p, lin_x, resp_c_out, alpha_out);
}

// Round 10
// 2543.741 us; speedup vs baseline: 1.2991x; 1.2991x over previous
//
#include <hip/hip_runtime.h>
#include <math.h>

#define Hd 512
#define Bd 64
#define Pd 32
#define Rd 4
#define Wd 64

typedef _Float16 h2v __attribute__((ext_vector_type(2)));

__device__ __forceinline__ float tanh_fast(float x) {
    float e = __expf(x + x);
    return 1.f - __fdividef(2.f, 1.f + e);
}

__device__ __forceinline__ float d2(unsigned a, unsigned b, float c) {
    return __builtin_amdgcn_fdot2(__builtin_bit_cast(h2v, a),
                                  __builtin_bit_cast(h2v, b), c, false);
}

__device__ __forceinline__ unsigned pk(float a, float b) {
    h2v p; p.x = (_Float16)a; p.y = (_Float16)b;
    return __builtin_bit_cast(unsigned, p);
}

// ---- build WAp = fp16-packed [W_a | lin_w^T] (256 h2 x 1024) + Wtp (256 h2 x 512) ----
// (proven rounds 6 & 8)
__global__ __launch_bounds__(256) void k_prep(const float* __restrict__ Wa,
                                              const float* __restrict__ lin_w,
                                              const float* __restrict__ Wt,
                                              unsigned* __restrict__ WAp,
                                              unsigned* __restrict__ Wtp) {
    __shared__ unsigned tile[32][33];
    int bx = blockIdx.x, by = blockIdx.y;
    int lane = threadIdx.x & 31, ty = threadIdx.x >> 5;
    for (int k = 0; k < 32; k += 8) {
        int h2 = by * 32 + ty + k, c = bx * 32 + lane;
        WAp[(size_t)h2 * 1024 + c] = pk(Wa[(size_t)(2 * h2) * Hd + c],
                                        Wa[(size_t)(2 * h2 + 1) * Hd + c]);
        Wtp[(size_t)h2 * 512 + c]  = pk(Wt[(size_t)(2 * h2) * Hd + c],
                                        Wt[(size_t)(2 * h2 + 1) * Hd + c]);
    }
    for (int k = 0; k < 32; k += 8) {
        int c_src = bx * 32 + ty + k, h2 = by * 32 + lane;
        float2 v = *(const float2*)&lin_w[(size_t)c_src * Hd + 2 * h2];
        tile[ty + k][lane] = pk(v.x, v.y);
    }
    __syncthreads();
    for (int k = 0; k < 32; k += 8) {
        int h2o = by * 32 + ty + k, co = bx * 32 + lane;
        WAp[(size_t)h2o * 1024 + 512 + co] = tile[lane][ty + k];
    }
}

// ---------------- Wctx[b,p,k] = sum_h ctx[b,p,h] * Wc[h,k]  (32 rows/block, proven) ----------------
__global__ __launch_bounds__(256) void k_wctx(const float* __restrict__ ctx_pbh,
                                              const float* __restrict__ Wc,
                                              float* __restrict__ Wctx) {
    __shared__ float As[32][Hd];
    int r0 = blockIdx.x * 32;
    int tid = threadIdx.x;
    for (int rr = 0; rr < 32; ++rr) {
        int bp = r0 + rr;
        int b = bp >> 5, p = bp & 31;
        const float* src = ctx_pbh + ((size_t)p * Bd + b) * Hd;
        for (int h = tid; h < Hd; h += 256) As[rr][h] = src[h];
    }
    __syncthreads();
    int c0 = tid, c1 = tid + 256;
    float acc0[32], acc1[32];
    #pragma unroll
    for (int rr = 0; rr < 32; ++rr) { acc0[rr] = 0.f; acc1[rr] = 0.f; }
    for (int h = 0; h < Hd; ++h) {
        float w0 = Wc[(size_t)h * Hd + c0], w1 = Wc[(size_t)h * Hd + c1];
        #pragma unroll
        for (int rr = 0; rr < 32; ++rr) {
            float a = As[rr][h];
            acc0[rr] += a * w0;
            acc1[rr] += a * w1;
        }
    }
    for (int rr = 0; rr < 32; ++rr) {
        Wctx[(size_t)(r0 + rr) * Hd + c0] = acc0[rr];
        Wctx[(size_t)(r0 + rr) * Hd + c1] = acc1[rr];
    }
}

// ---------------- rwh[t*256+row][c] = fp16(sum_h resp * Wt), dot2 path (proven) ----------------
__global__ __launch_bounds__(512) void k_rw(const float* __restrict__ resp,
                                            const unsigned* __restrict__ Wtp,
                                            unsigned short* __restrict__ rwh) {
    __shared__ unsigned As[32 * 256];
    int gr0 = blockIdx.x * 32, tid = threadIdx.x;
    for (int i = tid; i < 32 * 256; i += 512) {
        int rr = i >> 8, h2 = i & 255;
        int gr = gr0 + rr;
        int t = gr >> 8, row = gr & 255, r = row >> 6, bb = row & 63;
        float2 v = *(const float2*)(resp + (((size_t)(r * Wd + t)) * Bd + bb) * Hd + (h2 << 1));
        As[i] = pk(v.x, v.y);
    }
    __syncthreads();
    float acc[32];
    #pragma unroll
    for (int rr = 0; rr < 32; ++rr) acc[rr] = 0.f;
    const int c = tid;
    #pragma unroll 1
    for (int h2 = 0; h2 < 256; h2 += 4) {
        unsigned w0 = Wtp[((h2 + 0) << 9) + c];
        unsigned w1 = Wtp[((h2 + 1) << 9) + c];
        unsigned w2 = Wtp[((h2 + 2) << 9) + c];
        unsigned w3 = Wtp[((h2 + 3) << 9) + c];
        #pragma unroll
        for (int rr = 0; rr < 32; ++rr) {
            uint4 a4 = *(const uint4*)&As[(rr << 8) + h2];
            float s = acc[rr];
            s = d2(a4.x, w0, s); s = d2(a4.y, w1, s);
            s = d2(a4.z, w2, s); s = d2(a4.w, w3, s);
            acc[rr] = s;
        }
    }
    for (int rr = 0; rr < 32; ++rr)
        rwh[((size_t)(gr0 + rr) << 9) + c] =
            __builtin_bit_cast(unsigned short, (_Float16)acc[rr]);
}

// ---------------- persistent scan: 256 blocks (one per (r,b)), 1024 threads ----------------
// 3 barriers/step, all phases full-width, no state across barriers:
//  A1: zero sW tail + head GEMV (cols 0-511) -> atomicAdd sW head (rw preloaded).
//  A2||B: tail GEMV (cols 512-1023) with the tanh-score interleaved per 16-h2
//         load group (score reads only the finalized sW head).
//  C/D: lower 512 = softmax stats + alpha + ctx-reduce + tanh(tail) + atten pack;
//       upper 512 = rw(t+1) preload into sW head.
__global__ __launch_bounds__(1024, 4) void k_scan(
    const float* __restrict__ ctx,      // (P,B,H)
    const unsigned short* __restrict__ rwh, // (W*256, H) fp16
    const unsigned* __restrict__ WAp,   // (H/2, 1024) half2 pairs along h
    const float* __restrict__ Wctx,     // (B*P, H)
    const float* __restrict__ walpha,   // (H)
    const float* __restrict__ hidden,   // (R,B,H)
    const float* __restrict__ lin_p,    // (H,H)
    const float* __restrict__ lin_x,    // (H,H)
    float* __restrict__ out_resp,       // (R,B,H)
    float* __restrict__ out_alpha)      // (R,W,B,P)
{
    extern __shared__ float dynS[];
    float* sCtx   = dynS;                           // [32][512] 64 KB (persistent)
    float* sWctx  = dynS + 16384;                   // [32][512] 64 KB (persistent; epilogue scratch)
    float* sW     = dynS + 32768;                   // [1024]     4 KB
    float* sWal   = dynS + 33792;                   // [512]      2 KB
    float* sAtten = dynS + 34304;                   // [512]      2 KB
    float* scS    = dynS + 34816;                   // [32]
    unsigned* attenH = (unsigned*)(dynS + 34848);   // [256] half2 atten

    const int bid = blockIdx.x;
    const int r_ = bid >> 6, b_ = bid & 63;
    const int tid = threadIdx.x;
    const unsigned* rwU = (const unsigned*)rwh;

    // ---- identities ----
    const int q  = tid >> 8;                  // h2-quarter 0..3 (64 h2 each)
    const int c2 = (tid & 255) << 1;          // col pair 0..510 within a 512-col half
    const unsigned* __restrict__ whead = WAp + ((size_t)(q << 6)) * 1024 + c2;
    const unsigned* __restrict__ wtail = whead + 512;
    const int pB = tid >> 5, hc = tid & 31;   // score: 32 threads per p

    // ---- preamble: ctx[b], Wctx[b], walpha -> LDS; attenH=0; sW head = rw(0) ----
    for (int i = tid; i < 4096; i += 1024) {
        int p = i >> 7, h4 = (i & 127) << 2;
        *(float4*)&sCtx[(p << 9) + h4] =
            *(const float4*)&ctx[((size_t)(p * Bd + b_)) * Hd + h4];
        *(float4*)&sWctx[(p << 9) + h4] =
            *(const float4*)&Wctx[((size_t)(b_ * Pd + p)) * Hd + h4];
    }
    if (tid < Hd) sWal[tid] = walpha[tid];
    if (tid < 256) {
        attenH[tid] = 0u;
        unsigned u = rwU[((size_t)(r_ * 64 + b_)) * 256 + tid];
        h2v hp = __builtin_bit_cast(h2v, u);
        sW[2 * tid]     = (float)hp.x;
        sW[2 * tid + 1] = (float)hp.y;
    }
    __syncthreads();

    for (int t = 0; t < Wd; ++t) {
        // ================= A1: zero tail + head GEMV =================
        {
            if (tid < 512) sW[512 + tid] = 0.f;
            float2 acc = make_float2(0.f, 0.f);
            const unsigned* __restrict__ ah = attenH + (q << 6);
            #pragma unroll 8
            for (int j = 0; j < 64; ++j) {
                uint2 wv = *(const uint2*)(whead + (size_t)j * 1024);
                unsigned av = ah[j];
                acc.x = d2(av, wv.x, acc.x);
                acc.y = d2(av, wv.y, acc.y);
            }
            atomicAdd(&sW[c2],     acc.x);
            atomicAdd(&sW[c2 + 1], acc.y);
        }
        __syncthreads();   // B1: sW head complete (rw + head GEMV)

        // ================= A2 || B: tail GEMV with score interleaved =================
        {
            float2 acc = make_float2(0.f, 0.f);
            float sc = 0.f;
            const unsigned* __restrict__ ah = attenH + (q << 6);
            const float* __restrict__ wrow = sWctx + (pB << 9);
            #pragma unroll
            for (int g = 0; g < 4; ++g) {
                uint2 wv[16];
                #pragma unroll
                for (int j = 0; j < 16; ++j)
                    wv[j] = *(const uint2*)(wtail + (size_t)((g << 4) + j) * 1024);
                // score k-slice while the 16 loads are in flight (reads sW HEAD only)
                {
                    int h4 = (g << 7) + (hc << 2);
                    float4 wc = *(const float4*)&wrow[h4];
                    float4 wl = *(const float4*)&sWal[h4];
                    float4 v  = *(const float4*)&sW[h4];
                    sc += tanh_fast(wc.x + v.x) * wl.x + tanh_fast(wc.y + v.y) * wl.y
                        + tanh_fast(wc.z + v.z) * wl.z + tanh_fast(wc.w + v.w) * wl.w;
                }
                #pragma unroll
                for (int j = 0; j < 16; ++j) {
                    unsigned av = ah[(g << 4) + j];
                    acc.x = d2(av, wv[j].x, acc.x);
                    acc.y = d2(av, wv[j].y, acc.y);
                }
            }
            atomicAdd(&sW[512 + c2],     acc.x);
            atomicAdd(&sW[512 + c2 + 1], acc.y);
            #pragma unroll
            for (int off = 16; off; off >>= 1) sc += __shfl_down(sc, off, 32);
            if (hc == 0) scS[pB] = sc;
        }
        __syncthreads();   // B2: sW tail + scores complete

        // ================= C/D: update || rw(t+1) preload =================
        if (tid < 512) {
            float m = scS[0];
            #pragma unroll
            for (int p = 1; p < Pd; ++p) m = fmaxf(m, scS[p]);
            float sum = 0.f;
            #pragma unroll
            for (int p = 0; p < Pd; ++p) sum += __expf(scS[p] - m);
            float inv = __fdividef(1.f, sum);
            float a = 0.f;
            #pragma unroll 8
            for (int p = 0; p < Pd; ++p)
                a += __expf(scS[p] - m) * sCtx[(p << 9) + tid];
            a = a * inv + tanh_fast(sW[512 + tid]);
            sAtten[tid] = a;
            if (tid < Pd)
                out_alpha[(((size_t)r_ * Wd + t) * Bd + b_) * Pd + tid] =
                    __expf(scS[tid] - m) * inv;
            float an = __shfl_down(a, 1, 64);
            if (!(tid & 1)) attenH[tid >> 1] = pk(a, an);
        } else {
            const int tp = tid - 512;
            if (tp < 256 && t < Wd - 1) {
                unsigned u = rwU[((size_t)((t + 1) * 256 + r_ * 64 + b_)) * 256 + tp];
                h2v hp = __builtin_bit_cast(h2v, u);
                sW[2 * tp]     = (float)hp.x;
                sW[2 * tp + 1] = (float)hp.y;
            }
        }
        __syncthreads();   // B3: atten + next-step sW head ready
    }

    // ---- epilogue: resp_c = tanh(atten@lin_p^T + hidden@lin_x^T) ----
    if (tid < Hd) sWctx[tid] = hidden[((size_t)(r_ * Bd + b_)) * Hd + tid];
    __syncthreads();
    {
        const int half = tid >> 9;
        const int c = tid & 511;
        const int hb = half << 8;
        const float* __restrict__ lp = lin_p + (size_t)c * Hd + hb;
        const float* __restrict__ lx = lin_x + (size_t)c * Hd + hb;
        float f = 0.f;
        #pragma unroll 2
        for (int h = 0; h < 256; h += 4) {
            float4 lpv = *(const float4*)(lp + h);
            float4 lxv = *(const float4*)(lx + h);
            float4 aa  = *(const float4*)&sAtten[hb + h];
            float4 hh  = *(const float4*)&sWctx[hb + h];
            f += aa.x*lpv.x + aa.y*lpv.y + aa.z*lpv.z + aa.w*lpv.w
               + hh.x*lxv.x + hh.y*lxv.y + hh.z*lxv.z + hh.w*lxv.w;
        }
        sWctx[1024 + (half << 9) + c] = f;
    }
    __syncthreads();
    if (tid < Hd) {
        float f = sWctx[1024 + tid] + sWctx[1536 + tid];
        out_resp[((size_t)(r_ * Bd + b_)) * Hd + tid] = tanh_fast(f);
    }
}

extern "C" void kernel_launch(void* const* d_in, const int* in_sizes, int n_in,
                              void* d_out, int out_size, void* d_ws, size_t ws_size,
                              hipStream_t stream) {
    const float* ctx    = (const float*)d_in[0];  // (P,B,H)
    const float* resp   = (const float*)d_in[1];  // (R,W,B,H)
    const float* hidden = (const float*)d_in[2];  // (R,B,H)
    const float* Wc     = (const float*)d_in[3];
    const float* Wt     = (const float*)d_in[4];
    const float* Wa     = (const float*)d_in[5];
    const float* Walpha = (const float*)d_in[6];  // (H,1)
    const float* lin_w  = (const float*)d_in[7];
    const float* lin_p  = (const float*)d_in[8];
    const float* lin_x  = (const float*)d_in[9];

    float* out = (float*)d_out;
    float* resp_c_out = out;                       // R*B*H
    float* alpha_out  = out + Rd * Bd * Hd;        // R*W*B*P

    float* ws = (float*)d_ws;
    unsigned* WAp = (unsigned*)ws;                          //   262144 u32 (1 MB)
    unsigned* Wtp = (unsigned*)(ws + 262144);               //   131072 u32 (0.5 MB)
    float* Wctx   = ws + 393216;                            //  1048576 f32 (4 MB)
    unsigned short* rwh = (unsigned short*)(ws + 1441792);  //  8388608 u16 (16 MB)

    k_prep<<<dim3(16, 8), 256, 0, stream>>>(Wa, lin_w, Wt, WAp, Wtp);
    k_wctx<<<64, 256, 0, stream>>>(ctx, Wc, Wctx);
    k_rw<<<512, 512, 0, stream>>>(resp, Wtp, rwh);

    const int dyn_lds = 140416;                    // 35104 floats (~137 KB)
    static bool s_attr = false;
    if (!s_attr) {
        hipFuncSetAttribute((const void*)k_scan,
                            hipFuncAttributeMaxDynamicSharedMemorySize, dyn_lds);
        s_attr = true;
    }
    k_scan<<<256, 1024, dyn_lds, stream>>>(ctx, rwh, WAp, Wctx, Walpha, hidden,
                                           lin_p, lin_x, resp_c_out, alpha_out);
}

// Round 11
// 1337.596 us; speedup vs baseline: 2.4705x; 1.9017x over previous
//
#include <hip/hip_runtime.h>
#include <math.h>

#define Hd 512
#define Bd 64
#define Pd 32
#define Rd 4
#define Wd 64

typedef _Float16 h2v __attribute__((ext_vector_type(2)));

__device__ __forceinline__ float tanh_fast(float x) {
    float e = __expf(x + x);
    return 1.f - __fdividef(2.f, 1.f + e);
}

__device__ __forceinline__ float d2(unsigned a, unsigned b, float c) {
    return __builtin_amdgcn_fdot2(__builtin_bit_cast(h2v, a),
                                  __builtin_bit_cast(h2v, b), c, false);
}

__device__ __forceinline__ unsigned pk(float a, float b) {
    h2v p; p.x = (_Float16)a; p.y = (_Float16)b;
    return __builtin_bit_cast(unsigned, p);
}

// ---- build WAp = fp16-packed [W_a | lin_w^T] (256 h2 x 1024) + Wtp (256 h2 x 512) ----
__global__ __launch_bounds__(256) void k_prep(const float* __restrict__ Wa,
                                              const float* __restrict__ lin_w,
                                              const float* __restrict__ Wt,
                                              unsigned* __restrict__ WAp,
                                              unsigned* __restrict__ Wtp) {
    __shared__ unsigned tile[32][33];
    int bx = blockIdx.x, by = blockIdx.y;
    int lane = threadIdx.x & 31, ty = threadIdx.x >> 5;
    for (int k = 0; k < 32; k += 8) {
        int h2 = by * 32 + ty + k, c = bx * 32 + lane;
        WAp[(size_t)h2 * 1024 + c] = pk(Wa[(size_t)(2 * h2) * Hd + c],
                                        Wa[(size_t)(2 * h2 + 1) * Hd + c]);
        Wtp[(size_t)h2 * 512 + c]  = pk(Wt[(size_t)(2 * h2) * Hd + c],
                                        Wt[(size_t)(2 * h2 + 1) * Hd + c]);
    }
    for (int k = 0; k < 32; k += 8) {
        int c_src = bx * 32 + ty + k, h2 = by * 32 + lane;
        float2 v = *(const float2*)&lin_w[(size_t)c_src * Hd + 2 * h2];
        tile[ty + k][lane] = pk(v.x, v.y);
    }
    __syncthreads();
    for (int k = 0; k < 32; k += 8) {
        int h2o = by * 32 + ty + k, co = bx * 32 + lane;
        WAp[(size_t)h2o * 1024 + 512 + co] = tile[lane][ty + k];
    }
}

// ---------------- Wctx[b,p,k] = sum_h ctx[b,p,h] * Wc[h,k]  (32 rows/block) ----------------
__global__ __launch_bounds__(256) void k_wctx(const float* __restrict__ ctx_pbh,
                                              const float* __restrict__ Wc,
                                              float* __restrict__ Wctx) {
    __shared__ float As[32][Hd];
    int r0 = blockIdx.x * 32;
    int tid = threadIdx.x;
    for (int rr = 0; rr < 32; ++rr) {
        int bp = r0 + rr;
        int b = bp >> 5, p = bp & 31;
        const float* src = ctx_pbh + ((size_t)p * Bd + b) * Hd;
        for (int h = tid; h < Hd; h += 256) As[rr][h] = src[h];
    }
    __syncthreads();
    int c0 = tid, c1 = tid + 256;
    float acc0[32], acc1[32];
    #pragma unroll
    for (int rr = 0; rr < 32; ++rr) { acc0[rr] = 0.f; acc1[rr] = 0.f; }
    for (int h = 0; h < Hd; ++h) {
        float w0 = Wc[(size_t)h * Hd + c0], w1 = Wc[(size_t)h * Hd + c1];
        #pragma unroll
        for (int rr = 0; rr < 32; ++rr) {
            float a = As[rr][h];
            acc0[rr] += a * w0;
            acc1[rr] += a * w1;
        }
    }
    for (int rr = 0; rr < 32; ++rr) {
        Wctx[(size_t)(r0 + rr) * Hd + c0] = acc0[rr];
        Wctx[(size_t)(r0 + rr) * Hd + c1] = acc1[rr];
    }
}

// ---------------- rwh[t*256+row][c] = fp16(sum_h resp * Wt), dot2 path ----------------
__global__ __launch_bounds__(512) void k_rw(const float* __restrict__ resp,
                                            const unsigned* __restrict__ Wtp,
                                            unsigned short* __restrict__ rwh) {
    __shared__ unsigned As[32 * 256];
    int gr0 = blockIdx.x * 32, tid = threadIdx.x;
    for (int i = tid; i < 32 * 256; i += 512) {
        int rr = i >> 8, h2 = i & 255;
        int gr = gr0 + rr;
        int t = gr >> 8, row = gr & 255, r = row >> 6, bb = row & 63;
        float2 v = *(const float2*)(resp + (((size_t)(r * Wd + t)) * Bd + bb) * Hd + (h2 << 1));
        As[i] = pk(v.x, v.y);
    }
    __syncthreads();
    float acc[32];
    #pragma unroll
    for (int rr = 0; rr < 32; ++rr) acc[rr] = 0.f;
    const int c = tid;
    #pragma unroll 1
    for (int h2 = 0; h2 < 256; h2 += 4) {
        unsigned w0 = Wtp[((h2 + 0) << 9) + c];
        unsigned w1 = Wtp[((h2 + 1) << 9) + c];
        unsigned w2 = Wtp[((h2 + 2) << 9) + c];
        unsigned w3 = Wtp[((h2 + 3) << 9) + c];
        #pragma unroll
        for (int rr = 0; rr < 32; ++rr) {
            uint4 a4 = *(const uint4*)&As[(rr << 8) + h2];
            float s = acc[rr];
            s = d2(a4.x, w0, s); s = d2(a4.y, w1, s);
            s = d2(a4.z, w2, s); s = d2(a4.w, w3, s);
            acc[rr] = s;
        }
    }
    for (int rr = 0; rr < 32; ++rr)
        rwh[((size_t)(gr0 + rr) << 9) + c] =
            __builtin_bit_cast(unsigned short, (_Float16)acc[rr]);
}

// ---- CWh[b][p2][c] = fp16-pair( ctx[p]@WA )  pairs along p ----
// block = (b, octet of 8 p-rows), 1024 threads = 1024 columns
__global__ __launch_bounds__(1024) void k_cw(const float* __restrict__ ctx,
                                             const unsigned* __restrict__ WAp,
                                             unsigned* __restrict__ CWh) {
    __shared__ unsigned As[8 * 256];          // 8 rows x 256 h2 packed fp16
    const int b = blockIdx.x >> 2, oct = blockIdx.x & 3;
    const int tid = threadIdx.x;
    for (int i = tid; i < 8 * 256; i += 1024) {
        int rr = i >> 8, h2 = i & 255;
        int p = oct * 8 + rr;
        float2 v = *(const float2*)&ctx[((size_t)(p * Bd + b)) * Hd + (h2 << 1)];
        As[i] = pk(v.x, v.y);
    }
    __syncthreads();
    const int c = tid;
    float acc[8];
    #pragma unroll
    for (int rr = 0; rr < 8; ++rr) acc[rr] = 0.f;
    #pragma unroll 2
    for (int h2 = 0; h2 < 256; ++h2) {
        unsigned w = WAp[(size_t)h2 * 1024 + c];
        #pragma unroll
        for (int rr = 0; rr < 8; ++rr)
            acc[rr] = d2(As[(rr << 8) + h2], w, acc[rr]);
    }
    #pragma unroll
    for (int k = 0; k < 4; ++k) {
        int p2 = oct * 4 + k;
        CWh[((size_t)b * 16 + p2) * 1024 + c] = pk(acc[2 * k], acc[2 * k + 1]);
    }
}

// ---------------- persistent scan: 256 blocks (one per (r,b)), 1024 threads ----------------
// Linear decomposition: w(t) = u(t) + alpha(t-1)@CW + [rw(t),0],  u(t) = tanh(lw(t-1))@WA.
// The GEMV input tl(t)=tanh(tail of w(t)) is ready BEFORE score(t) -> GEMV u(t+1)
// overlaps score(t) in one phase. 3 barriers/step; no ctx-reduce in the loop.
//  P1: assemble w(t) (1 col/thread: u + 16 dot2 combo + rw); tail -> tanh -> tlH; zero u[nxt].
//  P2: GEMV u(t+1)=tlH@WA (4 cols x 64 h2/thread, load->dot, atomicAdd) + score interleaved.
//  P3: softmax (wave 0) -> alpha out, sAl, alphaH.
__global__ __launch_bounds__(1024, 4) void k_scan(
    const float* __restrict__ ctx,      // (P,B,H)
    const unsigned short* __restrict__ rwh, // (W*256, H) fp16
    const unsigned* __restrict__ WAp,   // (H/2, 1024) half2 pairs along h
    const float* __restrict__ Wctx,     // (B*P, H)
    const float* __restrict__ walpha,   // (H)
    const float* __restrict__ hidden,   // (R,B,H)
    const float* __restrict__ lin_p,    // (H,H)
    const float* __restrict__ lin_x,    // (H,H)
    const unsigned* __restrict__ CWh,   // (B,16,1024) fp16 pairs along p
    float* __restrict__ out_resp,       // (R,B,H)
    float* __restrict__ out_alpha)      // (R,W,B,P)
{
    extern __shared__ float dynS[];
    float* sWctx  = dynS;                           // [32][512] 64 KB (score; epilogue scratch)
    unsigned* CWs = (unsigned*)(dynS + 16384);      // [16][1024] 64 KB
    float* ubuf   = dynS + 32768;                   // [2][1024]  8 KB
    float* sW     = dynS + 34816;                   // [512]      2 KB (head of w)
    float* sWal   = dynS + 35328;                   // [512]      2 KB
    float* sTl    = dynS + 35840;                   // [512]      2 KB (fp32 tl, epilogue)
    float* sAtten = dynS + 36352;                   // [512]      2 KB (epilogue)
    float* scS    = dynS + 36864;                   // [32]
    float* sAl    = dynS + 36896;                   // [32]
    unsigned* alphaH = (unsigned*)(dynS + 36928);   // [16]
    unsigned* tlH    = (unsigned*)(dynS + 36944);   // [256]
    // total 37200 floats = 145.3 KB

    const int bid = blockIdx.x;
    const int r_ = bid >> 6, b_ = bid & 63;
    const int tid = threadIdx.x;

    // ---- identities ----
    const int q  = tid >> 8;                  // P2: h2-quarter (64 h2)
    const int c4 = (tid & 255) << 2;          // P2: col quad 0..1020
    const unsigned* __restrict__ wbase = WAp + ((size_t)(q << 6)) * 1024 + c4;
    const int pB = tid >> 5, hc = tid & 31;   // score: 32 threads per p

    // ---- preamble ----
    for (int i = tid; i < 4096; i += 1024) {
        int p = i >> 7, h4 = (i & 127) << 2;
        *(float4*)&sWctx[(p << 9) + h4] =
            *(const float4*)&Wctx[((size_t)(b_ * Pd + p)) * Hd + h4];
    }
    for (int i = tid; i < 16384; i += 1024)
        CWs[i] = CWh[(size_t)b_ * 16384 + i];
    if (tid < Hd) sWal[tid] = walpha[tid];
    ubuf[tid] = 0.f; ubuf[1024 + tid] = 0.f;
    if (tid < 256) tlH[tid] = 0u;
    if (tid < 16) alphaH[tid] = 0u;
    __syncthreads();

    for (int t = 0; t < Wd; ++t) {
        const int cur = t & 1, nxt = cur ^ 1;

        // ================= P1: assemble w(t), tl(t); zero u[nxt] =================
        {
            const int c = tid;
            float w = ubuf[(cur << 10) + c];
            #pragma unroll
            for (int p2 = 0; p2 < 16; ++p2)
                w = d2(alphaH[p2], CWs[(p2 << 10) + c], w);
            if (c < Hd) {
                unsigned short u = rwh[((size_t)(t * 256 + r_ * 64 + b_) << 9) + c];
                w += (float)__builtin_bit_cast(_Float16, u);
                sW[c] = w;
            } else {
                float tl = tanh_fast(w);
                sTl[c - Hd] = tl;
                float tn = __shfl_down(tl, 1, 64);
                if (!(c & 1)) tlH[(c - Hd) >> 1] = pk(tl, tn);
            }
            ubuf[(nxt << 10) + c] = 0.f;
        }
        __syncthreads();   // B1: w head, tlH, zeroed u[nxt] ready

        // ================= P2: GEMV u(t+1) = tlH@WA  (+ score interleaved) =================
        {
            float sc = 0.f;
            const float* __restrict__ wrow = sWctx + (pB << 9);
            if (t < Wd - 1 && t > 0) {
                float4 acc = make_float4(0.f, 0.f, 0.f, 0.f);
                #pragma unroll
                for (int g = 0; g < 4; ++g) {
                    #pragma unroll 8
                    for (int j = 0; j < 16; ++j) {
                        uint4 wv = *(const uint4*)(wbase + (size_t)((g << 4) + j) * 1024);
                        unsigned av = tlH[(q << 6) + (g << 4) + j];
                        acc.x = d2(av, wv.x, acc.x); acc.y = d2(av, wv.y, acc.y);
                        acc.z = d2(av, wv.z, acc.z); acc.w = d2(av, wv.w, acc.w);
                    }
                    {   // score slice g (reads finalized sW head only)
                        int h4 = (g << 7) + (hc << 2);
                        float4 wc = *(const float4*)&wrow[h4];
                        float4 wl = *(const float4*)&sWal[h4];
                        float4 v  = *(const float4*)&sW[h4];
                        sc += tanh_fast(wc.x + v.x) * wl.x + tanh_fast(wc.y + v.y) * wl.y
                            + tanh_fast(wc.z + v.z) * wl.z + tanh_fast(wc.w + v.w) * wl.w;
                    }
                }
                atomicAdd(&ubuf[(nxt << 10) + c4],     acc.x);
                atomicAdd(&ubuf[(nxt << 10) + c4 + 1], acc.y);
                atomicAdd(&ubuf[(nxt << 10) + c4 + 2], acc.z);
                atomicAdd(&ubuf[(nxt << 10) + c4 + 3], acc.w);
            } else {
                // t=0: tlH==0 (u(1)=0, buffer already zeroed); t=63: u unused
                #pragma unroll
                for (int g = 0; g < 4; ++g) {
                    int h4 = (g << 7) + (hc << 2);
                    float4 wc = *(const float4*)&wrow[h4];
                    float4 wl = *(const float4*)&sWal[h4];
                    float4 v  = *(const float4*)&sW[h4];
                    sc += tanh_fast(wc.x + v.x) * wl.x + tanh_fast(wc.y + v.y) * wl.y
                        + tanh_fast(wc.z + v.z) * wl.z + tanh_fast(wc.w + v.w) * wl.w;
                }
            }
            #pragma unroll
            for (int off = 16; off; off >>= 1) sc += __shfl_down(sc, off, 32);
            if (hc == 0) scS[pB] = sc;
        }
        __syncthreads();   // B2: u(t+1) + scores complete

        // ================= P3: softmax (wave 0) =================
        if (tid < 32) {
            float s = scS[tid];
            float m = s;
            #pragma unroll
            for (int off = 16; off; off >>= 1) m = fmaxf(m, __shfl_xor(m, off, 32));
            float e = __expf(s - m);
            float sum = e;
            #pragma unroll
            for (int off = 16; off; off >>= 1) sum += __shfl_xor(sum, off, 32);
            float al = e * __fdividef(1.f, sum);
            sAl[tid] = al;
            out_alpha[(((size_t)r_ * Wd + t) * Bd + b_) * Pd + tid] = al;
            float an = __shfl_down(al, 1, 32);
            if (!(tid & 1)) alphaH[tid >> 1] = pk(al, an);
        }
        __syncthreads();   // B3: alpha ready for next P1
    }

    // ---- epilogue: atten_final = sum_p alpha*ctx + tl;  resp_c = tanh(.@lin_p^T + hidden@lin_x^T)
    if (tid < Hd) {
        float a = sTl[tid];
        #pragma unroll 8
        for (int p = 0; p < Pd; ++p)
            a += sAl[p] * ctx[((size_t)(p * Bd + b_)) * Hd + tid];
        sAtten[tid] = a;
        sWctx[tid] = hidden[((size_t)(r_ * Bd + b_)) * Hd + tid];
    }
    __syncthreads();
    {
        const int half = tid >> 9;
        const int c = tid & 511;
        const int hb = half << 8;
        const float* __restrict__ lp = lin_p + (size_t)c * Hd + hb;
        const float* __restrict__ lx = lin_x + (size_t)c * Hd + hb;
        float f = 0.f;
        #pragma unroll 2
        for (int h = 0; h < 256; h += 4) {
            float4 lpv = *(const float4*)(lp + h);
            float4 lxv = *(const float4*)(lx + h);
            float4 aa  = *(const float4*)&sAtten[hb + h];
            float4 hh  = *(const float4*)&sWctx[hb + h];
            f += aa.x*lpv.x + aa.y*lpv.y + aa.z*lpv.z + aa.w*lpv.w
               + hh.x*lxv.x + hh.y*lxv.y + hh.z*lxv.z + hh.w*lxv.w;
        }
        sWctx[1024 + (half << 9) + c] = f;
    }
    __syncthreads();
    if (tid < Hd) {
        float f = sWctx[1024 + tid] + sWctx[1536 + tid];
        out_resp[((size_t)(r_ * Bd + b_)) * Hd + tid] = tanh_fast(f);
    }
}

extern "C" void kernel_launch(void* const* d_in, const int* in_sizes, int n_in,
                              void* d_out, int out_size, void* d_ws, size_t ws_size,
                              hipStream_t stream) {
    const float* ctx    = (const float*)d_in[0];  // (P,B,H)
    const float* resp   = (const float*)d_in[1];  // (R,W,B,H)
    const float* hidden = (const float*)d_in[2];  // (R,B,H)
    const float* Wc     = (const float*)d_in[3];
    const float* Wt     = (const float*)d_in[4];
    const float* Wa     = (const float*)d_in[5];
    const float* Walpha = (const float*)d_in[6];  // (H,1)
    const float* lin_w  = (const float*)d_in[7];
    const float* lin_p  = (const float*)d_in[8];
    const float* lin_x  = (const float*)d_in[9];

    float* out = (float*)d_out;
    float* resp_c_out = out;                       // R*B*H
    float* alpha_out  = out + Rd * Bd * Hd;        // R*W*B*P

    float* ws = (float*)d_ws;
    unsigned* WAp = (unsigned*)ws;                          //   262144 u32 (1 MB)
    unsigned* Wtp = (unsigned*)(ws + 262144);               //   131072 u32 (0.5 MB)
    float* Wctx   = ws + 393216;                            //  1048576 f32 (4 MB)
    unsigned short* rwh = (unsigned short*)(ws + 1441792);  //  8388608 u16 (16 MB)
    unsigned* CWh = (unsigned*)(ws + 5636096);              //  1048576 u32 (4 MB)
    // total ~25.5 MB

    k_prep<<<dim3(16, 8), 256, 0, stream>>>(Wa, lin_w, Wt, WAp, Wtp);
    k_wctx<<<64, 256, 0, stream>>>(ctx, Wc, Wctx);
    k_rw<<<512, 512, 0, stream>>>(resp, Wtp, rwh);
    k_cw<<<256, 1024, 0, stream>>>(ctx, WAp, CWh);

    const int dyn_lds = 148800;                    // 37200 floats (~145 KB)
    static bool s_attr = false;
    if (!s_attr) {
        hipFuncSetAttribute((const void*)k_scan,
                            hipFuncAttributeMaxDynamicSharedMemorySize, dyn_lds);
        s_attr = true;
    }
    k_scan<<<256, 1024, dyn_lds, stream>>>(ctx, rwh, WAp, Wctx, Walpha, hidden,
                                           lin_p, lin_x, CWh, resp_c_out, alpha_out);
}

// Round 12
// 1169.597 us; speedup vs baseline: 2.8254x; 1.1436x over previous
//
#include <hip/hip_runtime.h>
#include <math.h>

#define Hd 512
#define Bd 64
#define Pd 32
#define Rd 4
#define Wd 64

typedef _Float16 h2v __attribute__((ext_vector_type(2)));

__device__ __forceinline__ float tanh_fast(float x) {
    float e = __expf(x + x);
    return 1.f - __fdividef(2.f, 1.f + e);
}

__device__ __forceinline__ float d2(unsigned a, unsigned b, float c) {
    return __builtin_amdgcn_fdot2(__builtin_bit_cast(h2v, a),
                                  __builtin_bit_cast(h2v, b), c, false);
}

__device__ __forceinline__ unsigned pk(float a, float b) {
    h2v p; p.x = (_Float16)a; p.y = (_Float16)b;
    return __builtin_bit_cast(unsigned, p);
}

// ---- build WAp = fp16-packed [W_a | lin_w^T] (256 h2 x 1024) + Wtp (256 h2 x 512) ----
__global__ __launch_bounds__(256) void k_prep(const float* __restrict__ Wa,
                                              const float* __restrict__ lin_w,
                                              const float* __restrict__ Wt,
                                              unsigned* __restrict__ WAp,
                                              unsigned* __restrict__ Wtp) {
    __shared__ unsigned tile[32][33];
    int bx = blockIdx.x, by = blockIdx.y;
    int lane = threadIdx.x & 31, ty = threadIdx.x >> 5;
    for (int k = 0; k < 32; k += 8) {
        int h2 = by * 32 + ty + k, c = bx * 32 + lane;
        WAp[(size_t)h2 * 1024 + c] = pk(Wa[(size_t)(2 * h2) * Hd + c],
                                        Wa[(size_t)(2 * h2 + 1) * Hd + c]);
        Wtp[(size_t)h2 * 512 + c]  = pk(Wt[(size_t)(2 * h2) * Hd + c],
                                        Wt[(size_t)(2 * h2 + 1) * Hd + c]);
    }
    for (int k = 0; k < 32; k += 8) {
        int c_src = bx * 32 + ty + k, h2 = by * 32 + lane;
        float2 v = *(const float2*)&lin_w[(size_t)c_src * Hd + 2 * h2];
        tile[ty + k][lane] = pk(v.x, v.y);
    }
    __syncthreads();
    for (int k = 0; k < 32; k += 8) {
        int h2o = by * 32 + ty + k, co = bx * 32 + lane;
        WAp[(size_t)h2o * 1024 + 512 + co] = tile[lane][ty + k];
    }
}

// ---------------- Wctx[b,p,k] = sum_h ctx[b,p,h] * Wc[h,k]  (32 rows/block) ----------------
__global__ __launch_bounds__(256) void k_wctx(const float* __restrict__ ctx_pbh,
                                              const float* __restrict__ Wc,
                                              float* __restrict__ Wctx) {
    __shared__ float As[32][Hd];
    int r0 = blockIdx.x * 32;
    int tid = threadIdx.x;
    for (int rr = 0; rr < 32; ++rr) {
        int bp = r0 + rr;
        int b = bp >> 5, p = bp & 31;
        const float* src = ctx_pbh + ((size_t)p * Bd + b) * Hd;
        for (int h = tid; h < Hd; h += 256) As[rr][h] = src[h];
    }
    __syncthreads();
    int c0 = tid, c1 = tid + 256;
    float acc0[32], acc1[32];
    #pragma unroll
    for (int rr = 0; rr < 32; ++rr) { acc0[rr] = 0.f; acc1[rr] = 0.f; }
    for (int h = 0; h < Hd; ++h) {
        float w0 = Wc[(size_t)h * Hd + c0], w1 = Wc[(size_t)h * Hd + c1];
        #pragma unroll
        for (int rr = 0; rr < 32; ++rr) {
            float a = As[rr][h];
            acc0[rr] += a * w0;
            acc1[rr] += a * w1;
        }
    }
    for (int rr = 0; rr < 32; ++rr) {
        Wctx[(size_t)(r0 + rr) * Hd + c0] = acc0[rr];
        Wctx[(size_t)(r0 + rr) * Hd + c1] = acc1[rr];
    }
}

// ---------------- rwh[t*256+row][c] = fp16(sum_h resp * Wt), dot2 path ----------------
__global__ __launch_bounds__(512) void k_rw(const float* __restrict__ resp,
                                            const unsigned* __restrict__ Wtp,
                                            unsigned short* __restrict__ rwh) {
    __shared__ unsigned As[32 * 256];
    int gr0 = blockIdx.x * 32, tid = threadIdx.x;
    for (int i = tid; i < 32 * 256; i += 512) {
        int rr = i >> 8, h2 = i & 255;
        int gr = gr0 + rr;
        int t = gr >> 8, row = gr & 255, r = row >> 6, bb = row & 63;
        float2 v = *(const float2*)(resp + (((size_t)(r * Wd + t)) * Bd + bb) * Hd + (h2 << 1));
        As[i] = pk(v.x, v.y);
    }
    __syncthreads();
    float acc[32];
    #pragma unroll
    for (int rr = 0; rr < 32; ++rr) acc[rr] = 0.f;
    const int c = tid;
    #pragma unroll 1
    for (int h2 = 0; h2 < 256; h2 += 4) {
        unsigned w0 = Wtp[((h2 + 0) << 9) + c];
        unsigned w1 = Wtp[((h2 + 1) << 9) + c];
        unsigned w2 = Wtp[((h2 + 2) << 9) + c];
        unsigned w3 = Wtp[((h2 + 3) << 9) + c];
        #pragma unroll
        for (int rr = 0; rr < 32; ++rr) {
            uint4 a4 = *(const uint4*)&As[(rr << 8) + h2];
            float s = acc[rr];
            s = d2(a4.x, w0, s); s = d2(a4.y, w1, s);
            s = d2(a4.z, w2, s); s = d2(a4.w, w3, s);
            acc[rr] = s;
        }
    }
    for (int rr = 0; rr < 32; ++rr)
        rwh[((size_t)(gr0 + rr) << 9) + c] =
            __builtin_bit_cast(unsigned short, (_Float16)acc[rr]);
}

// ---- CWh[b][p2][c] = fp16-pair( ctx[p]@WA )  pairs along p ----
__global__ __launch_bounds__(1024) void k_cw(const float* __restrict__ ctx,
                                             const unsigned* __restrict__ WAp,
                                             unsigned* __restrict__ CWh) {
    __shared__ unsigned As[8 * 256];
    const int b = blockIdx.x >> 2, oct = blockIdx.x & 3;
    const int tid = threadIdx.x;
    for (int i = tid; i < 8 * 256; i += 1024) {
        int rr = i >> 8, h2 = i & 255;
        int p = oct * 8 + rr;
        float2 v = *(const float2*)&ctx[((size_t)(p * Bd + b)) * Hd + (h2 << 1)];
        As[i] = pk(v.x, v.y);
    }
    __syncthreads();
    const int c = tid;
    float acc[8];
    #pragma unroll
    for (int rr = 0; rr < 8; ++rr) acc[rr] = 0.f;
    #pragma unroll 2
    for (int h2 = 0; h2 < 256; ++h2) {
        unsigned w = WAp[(size_t)h2 * 1024 + c];
        #pragma unroll
        for (int rr = 0; rr < 8; ++rr)
            acc[rr] = d2(As[(rr << 8) + h2], w, acc[rr]);
    }
    #pragma unroll
    for (int k = 0; k < 4; ++k) {
        int p2 = oct * 4 + k;
        CWh[((size_t)b * 16 + p2) * 1024 + c] = pk(acc[2 * k], acc[2 * k + 1]);
    }
}

// ---------------- persistent scan: 256 blocks (one per (r,b)), 1024 threads ----------------
// Linear decomposition, strictly serial pure phases (3 barriers/step):
//  P1: redundant softmax(t-1) + assemble w(t) = sum(sPart) + alpha@CW + rw;
//      head -> sW, tail -> tanh -> tlH/sTl. (~1.3 us)
//  P2: PURE GEMV u(t+1) = tlH@WA, round-5 phase-A pattern verbatim, float4
//      stores to sPart (no atomics, no interleave). Skipped at t=0 / t=Wd-1.
//  P3: tanh-score (round-5 B pattern) -> scS.
__global__ __launch_bounds__(1024, 4) void k_scan(
    const float* __restrict__ ctx,      // (P,B,H)
    const unsigned short* __restrict__ rwh, // (W*256, H) fp16
    const unsigned* __restrict__ WAp,   // (H/2, 1024) half2 pairs along h
    const float* __restrict__ Wctx,     // (B*P, H)
    const float* __restrict__ walpha,   // (H)
    const float* __restrict__ hidden,   // (R,B,H)
    const float* __restrict__ lin_p,    // (H,H)
    const float* __restrict__ lin_x,    // (H,H)
    const unsigned* __restrict__ CWh,   // (B,16,1024) fp16 pairs along p
    float* __restrict__ out_resp,       // (R,B,H)
    float* __restrict__ out_alpha)      // (R,W,B,P)
{
    extern __shared__ float dynS[];
    float* sWctx  = dynS;                           // [32][512]  64 KB
    unsigned* CWs = (unsigned*)(dynS + 16384);      // [16][1024] 64 KB
    float* sPart  = dynS + 32768;                   // [4][1024]  16 KB (GEMV partials)
    float* sW     = dynS + 36864;                   // [512]       2 KB (head of w)
    float* sWal   = dynS + 37376;                   // [512]       2 KB
    float* sTl    = dynS + 37888;                   // [512]       2 KB (fp32 tl, epilogue)
    float* sAtten = dynS + 38400;                   // [512]       2 KB (epilogue)
    float* scS    = dynS + 38912;                   // [32]
    float* sAl    = dynS + 38944;                   // [32]
    unsigned* tlH = (unsigned*)(dynS + 38976);      // [256] half2 tl (16B aligned)
    // total 39232 floats = 153.25 KB

    const int bid = blockIdx.x;
    const int r_ = bid >> 6, b_ = bid & 63;
    const int tid = threadIdx.x;

    // ---- identities ----
    const int q  = tid >> 8;                  // P2: h2-quarter (64 h2)
    const int c4 = (tid & 255) << 2;          // P2: col quad 0..1020
    const unsigned* __restrict__ wap = WAp + ((size_t)(q << 6)) * 1024 + c4;
    const int pB = tid >> 5, hc = tid & 31;   // P3: 32 threads per p

    // ---- preamble ----
    for (int i = tid; i < 4096; i += 1024) {
        int p = i >> 7, h4 = (i & 127) << 2;
        *(float4*)&sWctx[(p << 9) + h4] =
            *(const float4*)&Wctx[((size_t)(b_ * Pd + p)) * Hd + h4];
        sPart[i] = 0.f;
    }
    for (int i = tid; i < 16384; i += 1024)
        CWs[i] = CWh[(size_t)b_ * 16384 + i];
    if (tid < Hd) sWal[tid] = walpha[tid];
    __syncthreads();

    for (int t = 0; t < Wd; ++t) {
        // ================= P1: softmax(t-1) + assemble w(t) + tanh tail =================
        {
            const int c = tid;
            float w = sPart[c] + sPart[1024 + c] + sPart[2048 + c] + sPart[3072 + c];
            if (t > 0) {
                float m = scS[0];
                #pragma unroll
                for (int p = 1; p < Pd; ++p) m = fmaxf(m, scS[p]);
                float e[Pd];
                float sum = 0.f;
                #pragma unroll
                for (int p = 0; p < Pd; ++p) { e[p] = __expf(scS[p] - m); sum += e[p]; }
                float inv = __fdividef(1.f, sum);
                #pragma unroll
                for (int p2 = 0; p2 < 16; ++p2)
                    w = d2(pk(e[2 * p2] * inv, e[2 * p2 + 1] * inv),
                           CWs[(p2 << 10) + c], w);
                if (tid < Pd)   // alpha(t-1) out (recompute exp: no runtime reg-index)
                    out_alpha[(((size_t)r_ * Wd + (t - 1)) * Bd + b_) * Pd + tid] =
                        __expf(scS[tid] - m) * inv;
            }
            if (c < Hd) {
                unsigned short u = rwh[((size_t)(t * 256 + r_ * 64 + b_) << 9) + c];
                w += (float)__builtin_bit_cast(_Float16, u);
                sW[c] = w;
            } else {
                float tl = tanh_fast(w);
                sTl[c - Hd] = tl;
                float tn = __shfl_down(tl, 1, 64);
                if (!(c & 1)) tlH[(c - Hd) >> 1] = pk(tl, tn);
            }
        }
        __syncthreads();   // B1: sW head, tlH ready; sPart free for P2

        // ================= P2: PURE GEMV u(t+1) = tlH @ WA =================
        if (t > 0 && t < Wd - 1) {
            float4 acc = make_float4(0.f, 0.f, 0.f, 0.f);
            #pragma unroll 4
            for (int jq = 0; jq < 16; ++jq) {
                const unsigned* wq = wap + ((size_t)jq << 12);
                uint4 w0 = *(const uint4*)(wq);
                uint4 w1 = *(const uint4*)(wq + 1024);
                uint4 w2 = *(const uint4*)(wq + 2048);
                uint4 w3 = *(const uint4*)(wq + 3072);
                uint4 a4 = *(const uint4*)&tlH[(q << 6) + (jq << 2)];
                acc.x = d2(a4.x, w0.x, acc.x); acc.y = d2(a4.x, w0.y, acc.y);
                acc.z = d2(a4.x, w0.z, acc.z); acc.w = d2(a4.x, w0.w, acc.w);
                acc.x = d2(a4.y, w1.x, acc.x); acc.y = d2(a4.y, w1.y, acc.y);
                acc.z = d2(a4.y, w1.z, acc.z); acc.w = d2(a4.y, w1.w, acc.w);
                acc.x = d2(a4.z, w2.x, acc.x); acc.y = d2(a4.z, w2.y, acc.y);
                acc.z = d2(a4.z, w2.z, acc.z); acc.w = d2(a4.z, w2.w, acc.w);
                acc.x = d2(a4.w, w3.x, acc.x); acc.y = d2(a4.w, w3.y, acc.y);
                acc.z = d2(a4.w, w3.z, acc.z); acc.w = d2(a4.w, w3.w, acc.w);
            }
            *(float4*)&sPart[(q << 10) + c4] = acc;
        } else if (t == 0) {
            // tl(0)=0 -> u(1)=0; sPart already zero (preamble, nothing wrote it)
        }
        __syncthreads();   // B2: sPart = u(t+1) partials

        // ================= P3: tanh-score -> scS =================
        {
            const float* __restrict__ wrow = sWctx + (pB << 9);
            float sc = 0.f;
            #pragma unroll
            for (int k = 0; k < 4; ++k) {
                int h4 = (k << 7) + (hc << 2);
                float4 wc = *(const float4*)&wrow[h4];
                float4 wl = *(const float4*)&sWal[h4];
                float4 v  = *(const float4*)&sW[h4];
                sc += tanh_fast(wc.x + v.x) * wl.x + tanh_fast(wc.y + v.y) * wl.y
                    + tanh_fast(wc.z + v.z) * wl.z + tanh_fast(wc.w + v.w) * wl.w;
            }
            #pragma unroll
            for (int off = 16; off; off >>= 1) sc += __shfl_down(sc, off, 32);
            if (hc == 0) scS[pB] = sc;
        }
        __syncthreads();   // B3: scores ready for next P1
    }

    // ---- epilogue: softmax(63) -> alpha out + sAl; atten_final; output GEMM ----
    if (tid < 32) {
        float s = scS[tid];
        float m = s;
        #pragma unroll
        for (int off = 16; off; off >>= 1) m = fmaxf(m, __shfl_xor(m, off, 32));
        float e = __expf(s - m);
        float sum = e;
        #pragma unroll
        for (int off = 16; off; off >>= 1) sum += __shfl_xor(sum, off, 32);
        float al = e * __fdividef(1.f, sum);
        sAl[tid] = al;
        out_alpha[(((size_t)r_ * Wd + (Wd - 1)) * Bd + b_) * Pd + tid] = al;
    }
    __syncthreads();
    if (tid < Hd) {
        float a = sTl[tid];
        #pragma unroll 8
        for (int p = 0; p < Pd; ++p)
            a += sAl[p] * ctx[((size_t)(p * Bd + b_)) * Hd + tid];
        sAtten[tid] = a;
        sWctx[tid] = hidden[((size_t)(r_ * Bd + b_)) * Hd + tid];
    }
    __syncthreads();
    {
        const int half = tid >> 9;
        const int c = tid & 511;
        const int hb = half << 8;
        const float* __restrict__ lp = lin_p + (size_t)c * Hd + hb;
        const float* __restrict__ lx = lin_x + (size_t)c * Hd + hb;
        float f = 0.f;
        #pragma unroll 2
        for (int h = 0; h < 256; h += 4) {
            float4 lpv = *(const float4*)(lp + h);
            float4 lxv = *(const float4*)(lx + h);
            float4 aa  = *(const float4*)&sAtten[hb + h];
            float4 hh  = *(const float4*)&sWctx[hb + h];
            f += aa.x*lpv.x + aa.y*lpv.y + aa.z*lpv.z + aa.w*lpv.w
               + hh.x*lxv.x + hh.y*lxv.y + hh.z*lxv.z + hh.w*lxv.w;
        }
        sWctx[1024 + (half << 9) + c] = f;
    }
    __syncthreads();
    if (tid < Hd) {
        float f = sWctx[1024 + tid] + sWctx[1536 + tid];
        out_resp[((size_t)(r_ * Bd + b_)) * Hd + tid] = tanh_fast(f);
    }
}

extern "C" void kernel_launch(void* const* d_in, const int* in_sizes, int n_in,
                              void* d_out, int out_size, void* d_ws, size_t ws_size,
                              hipStream_t stream) {
    const float* ctx    = (const float*)d_in[0];  // (P,B,H)
    const float* resp   = (const float*)d_in[1];  // (R,W,B,H)
    const float* hidden = (const float*)d_in[2];  // (R,B,H)
    const float* Wc     = (const float*)d_in[3];
    const float* Wt     = (const float*)d_in[4];
    const float* Wa     = (const float*)d_in[5];
    const float* Walpha = (const float*)d_in[6];  // (H,1)
    const float* lin_w  = (const float*)d_in[7];
    const float* lin_p  = (const float*)d_in[8];
    const float* lin_x  = (const float*)d_in[9];

    float* out = (float*)d_out;
    float* resp_c_out = out;                       // R*B*H
    float* alpha_out  = out + Rd * Bd * Hd;        // R*W*B*P

    float* ws = (float*)d_ws;
    unsigned* WAp = (unsigned*)ws;                          //   262144 u32 (1 MB)
    unsigned* Wtp = (unsigned*)(ws + 262144);               //   131072 u32 (0.5 MB)
    float* Wctx   = ws + 393216;                            //  1048576 f32 (4 MB)
    unsigned short* rwh = (unsigned short*)(ws + 1441792);  //  8388608 u16 (16 MB)
    unsigned* CWh = (unsigned*)(ws + 5636096);              //  1048576 u32 (4 MB)
    // total ~25.5 MB

    k_prep<<<dim3(16, 8), 256, 0, stream>>>(Wa, lin_w, Wt, WAp, Wtp);
    k_wctx<<<64, 256, 0, stream>>>(ctx, Wc, Wctx);
    k_rw<<<512, 512, 0, stream>>>(resp, Wtp, rwh);
    k_cw<<<256, 1024, 0, stream>>>(ctx, WAp, CWh);

    const int dyn_lds = 156928;                    // 39232 floats (~153 KB)
    static bool s_attr = false;
    if (!s_attr) {
        hipFuncSetAttribute((const void*)k_scan,
                            hipFuncAttributeMaxDynamicSharedMemorySize, dyn_lds);
        s_attr = true;
    }
    k_scan<<<256, 1024, dyn_lds, stream>>>(ctx, rwh, WAp, Wctx, Walpha, hidden,
                                           lin_p, lin_x, CWh, resp_c_out, alpha_out);
}

// Round 13
// 1013.633 us; speedup vs baseline: 3.2601x; 1.1539x over previous
//
#include <hip/hip_runtime.h>
#include <math.h>

#define Hd 512
#define Bd 64
#define Pd 32
#define Rd 4
#define Wd 64

typedef _Float16 h2v __attribute__((ext_vector_type(2)));

__device__ __forceinline__ float tanh_fast(float x) {
    float e = __expf(x + x);
    return 1.f - __fdividef(2.f, 1.f + e);
}

__device__ __forceinline__ float d2(unsigned a, unsigned b, float c) {
    return __builtin_amdgcn_fdot2(__builtin_bit_cast(h2v, a),
                                  __builtin_bit_cast(h2v, b), c, false);
}

__device__ __forceinline__ unsigned pk(float a, float b) {
    h2v p; p.x = (_Float16)a; p.y = (_Float16)b;
    return __builtin_bit_cast(unsigned, p);
}

// ---- build WAp = fp16-packed [W_a | lin_w^T] (256 h2 x 1024)
// ----       + Wtp (256 h2 x 512) + Wcp (256 h2 x 512) ----
__global__ __launch_bounds__(256) void k_prep(const float* __restrict__ Wa,
                                              const float* __restrict__ lin_w,
                                              const float* __restrict__ Wt,
                                              const float* __restrict__ Wc,
                                              unsigned* __restrict__ WAp,
                                              unsigned* __restrict__ Wtp,
                                              unsigned* __restrict__ Wcp) {
    __shared__ unsigned tile[32][33];
    int bx = blockIdx.x, by = blockIdx.y;
    int lane = threadIdx.x & 31, ty = threadIdx.x >> 5;
    for (int k = 0; k < 32; k += 8) {
        int h2 = by * 32 + ty + k, c = bx * 32 + lane;
        WAp[(size_t)h2 * 1024 + c] = pk(Wa[(size_t)(2 * h2) * Hd + c],
                                        Wa[(size_t)(2 * h2 + 1) * Hd + c]);
        Wtp[(size_t)h2 * 512 + c]  = pk(Wt[(size_t)(2 * h2) * Hd + c],
                                        Wt[(size_t)(2 * h2 + 1) * Hd + c]);
        Wcp[(size_t)h2 * 512 + c]  = pk(Wc[(size_t)(2 * h2) * Hd + c],
                                        Wc[(size_t)(2 * h2 + 1) * Hd + c]);
    }
    for (int k = 0; k < 32; k += 8) {
        int c_src = bx * 32 + ty + k, h2 = by * 32 + lane;
        float2 v = *(const float2*)&lin_w[(size_t)c_src * Hd + 2 * h2];
        tile[ty + k][lane] = pk(v.x, v.y);
    }
    __syncthreads();
    for (int k = 0; k < 32; k += 8) {
        int h2o = by * 32 + ty + k, co = bx * 32 + lane;
        WAp[(size_t)h2o * 1024 + 512 + co] = tile[lane][ty + k];
    }
}

// ---------------- Wctx via dot2: 256 blocks x 8 rows (k_rw pattern) ----------------
__global__ __launch_bounds__(512) void k_wctx2(const float* __restrict__ ctx_pbh,
                                               const unsigned* __restrict__ Wcp,
                                               float* __restrict__ Wctx) {
    __shared__ unsigned As[8 * 256];       // 8 rows x 256 h2, packed fp16
    int gr0 = blockIdx.x * 8, tid = threadIdx.x;
    for (int i = tid; i < 8 * 256; i += 512) {
        int rr = i >> 8, h2 = i & 255;
        int gr = gr0 + rr, b = gr >> 5, p = gr & 31;
        float2 v = *(const float2*)&ctx_pbh[((size_t)(p * Bd + b)) * Hd + (h2 << 1)];
        As[i] = pk(v.x, v.y);
    }
    __syncthreads();
    float acc[8];
    #pragma unroll
    for (int rr = 0; rr < 8; ++rr) acc[rr] = 0.f;
    const int c = tid;
    #pragma unroll 1
    for (int h2 = 0; h2 < 256; h2 += 4) {
        unsigned w0 = Wcp[((h2 + 0) << 9) + c];
        unsigned w1 = Wcp[((h2 + 1) << 9) + c];
        unsigned w2 = Wcp[((h2 + 2) << 9) + c];
        unsigned w3 = Wcp[((h2 + 3) << 9) + c];
        #pragma unroll
        for (int rr = 0; rr < 8; ++rr) {
            uint4 a4 = *(const uint4*)&As[(rr << 8) + h2];
            float s = acc[rr];
            s = d2(a4.x, w0, s); s = d2(a4.y, w1, s);
            s = d2(a4.z, w2, s); s = d2(a4.w, w3, s);
            acc[rr] = s;
        }
    }
    for (int rr = 0; rr < 8; ++rr)
        Wctx[(size_t)(gr0 + rr) * Hd + c] = acc[rr];
}

// ---------------- rwh[t*256+row][c] = fp16(sum_h resp * Wt), dot2 path ----------------
__global__ __launch_bounds__(512) void k_rw(const float* __restrict__ resp,
                                            const unsigned* __restrict__ Wtp,
                                            unsigned short* __restrict__ rwh) {
    __shared__ unsigned As[32 * 256];
    int gr0 = blockIdx.x * 32, tid = threadIdx.x;
    for (int i = tid; i < 32 * 256; i += 512) {
        int rr = i >> 8, h2 = i & 255;
        int gr = gr0 + rr;
        int t = gr >> 8, row = gr & 255, r = row >> 6, bb = row & 63;
        float2 v = *(const float2*)(resp + (((size_t)(r * Wd + t)) * Bd + bb) * Hd + (h2 << 1));
        As[i] = pk(v.x, v.y);
    }
    __syncthreads();
    float acc[32];
    #pragma unroll
    for (int rr = 0; rr < 32; ++rr) acc[rr] = 0.f;
    const int c = tid;
    #pragma unroll 1
    for (int h2 = 0; h2 < 256; h2 += 4) {
        unsigned w0 = Wtp[((h2 + 0) << 9) + c];
        unsigned w1 = Wtp[((h2 + 1) << 9) + c];
        unsigned w2 = Wtp[((h2 + 2) << 9) + c];
        unsigned w3 = Wtp[((h2 + 3) << 9) + c];
        #pragma unroll
        for (int rr = 0; rr < 32; ++rr) {
            uint4 a4 = *(const uint4*)&As[(rr << 8) + h2];
            float s = acc[rr];
            s = d2(a4.x, w0, s); s = d2(a4.y, w1, s);
            s = d2(a4.z, w2, s); s = d2(a4.w, w3, s);
            acc[rr] = s;
        }
    }
    for (int rr = 0; rr < 32; ++rr)
        rwh[((size_t)(gr0 + rr) << 9) + c] =
            __builtin_bit_cast(unsigned short, (_Float16)acc[rr]);
}

// ---- CWh[b][p2][c] = fp16-pair( ctx[p]@WA )  pairs along p (uint4 As reads) ----
__global__ __launch_bounds__(1024) void k_cw(const float* __restrict__ ctx,
                                             const unsigned* __restrict__ WAp,
                                             unsigned* __restrict__ CWh) {
    __shared__ unsigned As[8 * 256];
    const int b = blockIdx.x >> 2, oct = blockIdx.x & 3;
    const int tid = threadIdx.x;
    for (int i = tid; i < 8 * 256; i += 1024) {
        int rr = i >> 8, h2 = i & 255;
        int p = oct * 8 + rr;
        float2 v = *(const float2*)&ctx[((size_t)(p * Bd + b)) * Hd + (h2 << 1)];
        As[i] = pk(v.x, v.y);
    }
    __syncthreads();
    const int c = tid;
    float acc[8];
    #pragma unroll
    for (int rr = 0; rr < 8; ++rr) acc[rr] = 0.f;
    #pragma unroll 1
    for (int h2 = 0; h2 < 256; h2 += 4) {
        unsigned w0 = WAp[((size_t)(h2 + 0)) * 1024 + c];
        unsigned w1 = WAp[((size_t)(h2 + 1)) * 1024 + c];
        unsigned w2 = WAp[((size_t)(h2 + 2)) * 1024 + c];
        unsigned w3 = WAp[((size_t)(h2 + 3)) * 1024 + c];
        #pragma unroll
        for (int rr = 0; rr < 8; ++rr) {
            uint4 a4 = *(const uint4*)&As[(rr << 8) + h2];
            float s = acc[rr];
            s = d2(a4.x, w0, s); s = d2(a4.y, w1, s);
            s = d2(a4.z, w2, s); s = d2(a4.w, w3, s);
            acc[rr] = s;
        }
    }
    #pragma unroll
    for (int k = 0; k < 4; ++k) {
        int p2 = oct * 4 + k;
        CWh[((size_t)b * 16 + p2) * 1024 + c] = pk(acc[2 * k], acc[2 * k + 1]);
    }
}

// ---------------- persistent scan: 256 blocks (one per (r,b)), 1024 threads ----------------
// (structure proven in round 12; only change: rw load hoisted to top of P1)
__global__ __launch_bounds__(1024, 4) void k_scan(
    const float* __restrict__ ctx,      // (P,B,H)
    const unsigned short* __restrict__ rwh, // (W*256, H) fp16
    const unsigned* __restrict__ WAp,   // (H/2, 1024) half2 pairs along h
    const float* __restrict__ Wctx,     // (B*P, H)
    const float* __restrict__ walpha,   // (H)
    const float* __restrict__ hidden,   // (R,B,H)
    const float* __restrict__ lin_p,    // (H,H)
    const float* __restrict__ lin_x,    // (H,H)
    const unsigned* __restrict__ CWh,   // (B,16,1024) fp16 pairs along p
    float* __restrict__ out_resp,       // (R,B,H)
    float* __restrict__ out_alpha)      // (R,W,B,P)
{
    extern __shared__ float dynS[];
    float* sWctx  = dynS;                           // [32][512]  64 KB
    unsigned* CWs = (unsigned*)(dynS + 16384);      // [16][1024] 64 KB
    float* sPart  = dynS + 32768;                   // [4][1024]  16 KB (GEMV partials)
    float* sW     = dynS + 36864;                   // [512]       2 KB (head of w)
    float* sWal   = dynS + 37376;                   // [512]       2 KB
    float* sTl    = dynS + 37888;                   // [512]       2 KB (fp32 tl, epilogue)
    float* sAtten = dynS + 38400;                   // [512]       2 KB (epilogue)
    float* scS    = dynS + 38912;                   // [32]
    float* sAl    = dynS + 38944;                   // [32]
    unsigned* tlH = (unsigned*)(dynS + 38976);      // [256] half2 tl (16B aligned)

    const int bid = blockIdx.x;
    const int r_ = bid >> 6, b_ = bid & 63;
    const int tid = threadIdx.x;

    // ---- identities ----
    const int q  = tid >> 8;                  // P2: h2-quarter (64 h2)
    const int c4 = (tid & 255) << 2;          // P2: col quad 0..1020
    const unsigned* __restrict__ wap = WAp + ((size_t)(q << 6)) * 1024 + c4;
    const int pB = tid >> 5, hc = tid & 31;   // P3: 32 threads per p

    // ---- preamble ----
    for (int i = tid; i < 4096; i += 1024) {
        int p = i >> 7, h4 = (i & 127) << 2;
        *(float4*)&sWctx[(p << 9) + h4] =
            *(const float4*)&Wctx[((size_t)(b_ * Pd + p)) * Hd + h4];
        sPart[i] = 0.f;
    }
    for (int i = tid; i < 16384; i += 1024)
        CWs[i] = CWh[(size_t)b_ * 16384 + i];
    if (tid < Hd) sWal[tid] = walpha[tid];
    __syncthreads();

    for (int t = 0; t < Wd; ++t) {
        // ================= P1: softmax(t-1) + assemble w(t) + tanh tail =================
        {
            const int c = tid;
            // hoist: issue the rw global load before the softmax VALU chain
            unsigned short urw = 0;
            if (c < Hd)
                urw = rwh[((size_t)(t * 256 + r_ * 64 + b_) << 9) + c];
            float w = sPart[c] + sPart[1024 + c] + sPart[2048 + c] + sPart[3072 + c];
            if (t > 0) {
                float m = scS[0];
                #pragma unroll
                for (int p = 1; p < Pd; ++p) m = fmaxf(m, scS[p]);
                float e[Pd];
                float sum = 0.f;
                #pragma unroll
                for (int p = 0; p < Pd; ++p) { e[p] = __expf(scS[p] - m); sum += e[p]; }
                float inv = __fdividef(1.f, sum);
                #pragma unroll
                for (int p2 = 0; p2 < 16; ++p2)
                    w = d2(pk(e[2 * p2] * inv, e[2 * p2 + 1] * inv),
                           CWs[(p2 << 10) + c], w);
                if (tid < Pd)
                    out_alpha[(((size_t)r_ * Wd + (t - 1)) * Bd + b_) * Pd + tid] =
                        __expf(scS[tid] - m) * inv;
            }
            if (c < Hd) {
                w += (float)__builtin_bit_cast(_Float16, urw);
                sW[c] = w;
            } else {
                float tl = tanh_fast(w);
                sTl[c - Hd] = tl;
                float tn = __shfl_down(tl, 1, 64);
                if (!(c & 1)) tlH[(c - Hd) >> 1] = pk(tl, tn);
            }
        }
        __syncthreads();   // B1: sW head, tlH ready; sPart free for P2

        // ================= P2: PURE GEMV u(t+1) = tlH @ WA =================
        if (t > 0 && t < Wd - 1) {
            float4 acc = make_float4(0.f, 0.f, 0.f, 0.f);
            #pragma unroll 4
            for (int jq = 0; jq < 16; ++jq) {
                const unsigned* wq = wap + ((size_t)jq << 12);
                uint4 w0 = *(const uint4*)(wq);
                uint4 w1 = *(const uint4*)(wq + 1024);
                uint4 w2 = *(const uint4*)(wq + 2048);
                uint4 w3 = *(const uint4*)(wq + 3072);
                uint4 a4 = *(const uint4*)&tlH[(q << 6) + (jq << 2)];
                acc.x = d2(a4.x, w0.x, acc.x); acc.y = d2(a4.x, w0.y, acc.y);
                acc.z = d2(a4.x, w0.z, acc.z); acc.w = d2(a4.x, w0.w, acc.w);
                acc.x = d2(a4.y, w1.x, acc.x); acc.y = d2(a4.y, w1.y, acc.y);
                acc.z = d2(a4.y, w1.z, acc.z); acc.w = d2(a4.y, w1.w, acc.w);
                acc.x = d2(a4.z, w2.x, acc.x); acc.y = d2(a4.z, w2.y, acc.y);
                acc.z = d2(a4.z, w2.z, acc.z); acc.w = d2(a4.z, w2.w, acc.w);
                acc.x = d2(a4.w, w3.x, acc.x); acc.y = d2(a4.w, w3.y, acc.y);
                acc.z = d2(a4.w, w3.z, acc.z); acc.w = d2(a4.w, w3.w, acc.w);
            }
            *(float4*)&sPart[(q << 10) + c4] = acc;
        }
        __syncthreads();   // B2: sPart = u(t+1) partials

        // ================= P3: tanh-score -> scS =================
        {
            const float* __restrict__ wrow = sWctx + (pB << 9);
            float sc = 0.f;
            #pragma unroll
            for (int k = 0; k < 4; ++k) {
                int h4 = (k << 7) + (hc << 2);
                float4 wc = *(const float4*)&wrow[h4];
                float4 wl = *(const float4*)&sWal[h4];
                float4 v  = *(const float4*)&sW[h4];
                sc += tanh_fast(wc.x + v.x) * wl.x + tanh_fast(wc.y + v.y) * wl.y
                    + tanh_fast(wc.z + v.z) * wl.z + tanh_fast(wc.w + v.w) * wl.w;
            }
            #pragma unroll
            for (int off = 16; off; off >>= 1) sc += __shfl_down(sc, off, 32);
            if (hc == 0) scS[pB] = sc;
        }
        __syncthreads();   // B3: scores ready for next P1
    }

    // ---- epilogue: softmax(63) -> alpha out + sAl; atten_final; output GEMM ----
    if (tid < 32) {
        float s = scS[tid];
        float m = s;
        #pragma unroll
        for (int off = 16; off; off >>= 1) m = fmaxf(m, __shfl_xor(m, off, 32));
        float e = __expf(s - m);
        float sum = e;
        #pragma unroll
        for (int off = 16; off; off >>= 1) sum += __shfl_xor(sum, off, 32);
        float al = e * __fdividef(1.f, sum);
        sAl[tid] = al;
        out_alpha[(((size_t)r_ * Wd + (Wd - 1)) * Bd + b_) * Pd + tid] = al;
    }
    __syncthreads();
    if (tid < Hd) {
        float a = sTl[tid];
        #pragma unroll 8
        for (int p = 0; p < Pd; ++p)
            a += sAl[p] * ctx[((size_t)(p * Bd + b_)) * Hd + tid];
        sAtten[tid] = a;
        sWctx[tid] = hidden[((size_t)(r_ * Bd + b_)) * Hd + tid];
    }
    __syncthreads();
    {
        const int half = tid >> 9;
        const int c = tid & 511;
        const int hb = half << 8;
        const float* __restrict__ lp = lin_p + (size_t)c * Hd + hb;
        const float* __restrict__ lx = lin_x + (size_t)c * Hd + hb;
        float f = 0.f;
        #pragma unroll 2
        for (int h = 0; h < 256; h += 4) {
            float4 lpv = *(const float4*)(lp + h);
            float4 lxv = *(const float4*)(lx + h);
            float4 aa  = *(const float4*)&sAtten[hb + h];
            float4 hh  = *(const float4*)&sWctx[hb + h];
            f += aa.x*lpv.x + aa.y*lpv.y + aa.z*lpv.z + aa.w*lpv.w
               + hh.x*lxv.x + hh.y*lxv.y + hh.z*lxv.z + hh.w*lxv.w;
        }
        sWctx[1024 + (half << 9) + c] = f;
    }
    __syncthreads();
    if (tid < Hd) {
        float f = sWctx[1024 + tid] + sWctx[1536 + tid];
        out_resp[((size_t)(r_ * Bd + b_)) * Hd + tid] = tanh_fast(f);
    }
}

extern "C" void kernel_launch(void* const* d_in, const int* in_sizes, int n_in,
                              void* d_out, int out_size, void* d_ws, size_t ws_size,
                              hipStream_t stream) {
    const float* ctx    = (const float*)d_in[0];  // (P,B,H)
    const float* resp   = (const float*)d_in[1];  // (R,W,B,H)
    const float* hidden = (const float*)d_in[2];  // (R,B,H)
    const float* Wc     = (const float*)d_in[3];
    const float* Wt     = (const float*)d_in[4];
    const float* Wa     = (const float*)d_in[5];
    const float* Walpha = (const float*)d_in[6];  // (H,1)
    const float* lin_w  = (const float*)d_in[7];
    const float* lin_p  = (const float*)d_in[8];
    const float* lin_x  = (const float*)d_in[9];

    float* out = (float*)d_out;
    float* resp_c_out = out;                       // R*B*H
    float* alpha_out  = out + Rd * Bd * Hd;        // R*W*B*P

    float* ws = (float*)d_ws;
    unsigned* WAp = (unsigned*)ws;                          //   262144 u32 (1 MB)
    unsigned* Wtp = (unsigned*)(ws + 262144);               //   131072 u32 (0.5 MB)
    unsigned* Wcp = (unsigned*)(ws + 393216);               //   131072 u32 (0.5 MB)
    float* Wctx   = ws + 524288;                            //  1048576 f32 (4 MB)
    unsigned short* rwh = (unsigned short*)(ws + 1572864);  //  8388608 u16 (16 MB)
    unsigned* CWh = (unsigned*)(ws + 5767168);              //  1048576 u32 (4 MB)
    // total ~27.3 MB

    k_prep<<<dim3(16, 8), 256, 0, stream>>>(Wa, lin_w, Wt, Wc, WAp, Wtp, Wcp);
    k_wctx2<<<256, 512, 0, stream>>>(ctx, Wcp, Wctx);
    k_rw<<<512, 512, 0, stream>>>(resp, Wtp, rwh);
    k_cw<<<256, 1024, 0, stream>>>(ctx, WAp, CWh);

    const int dyn_lds = 156928;                    // 39232 floats (~153 KB)
    static bool s_attr = false;
    if (!s_attr) {
        hipFuncSetAttribute((const void*)k_scan,
                            hipFuncAttributeMaxDynamicSharedMemorySize, dyn_lds);
        s_attr = true;
    }
    k_scan<<<256, 1024, dyn_lds, stream>>>(ctx, rwh, WAp, Wctx, Walpha, hidden,
                                           lin_p, lin_x, CWh, resp_c_out, alpha_out);
}

// Round 14
// 931.324 us; speedup vs baseline: 3.5482x; 1.0884x over previous
//
#include <hip/hip_runtime.h>
#include <math.h>

#define Hd 512
#define Bd 64
#define Pd 32
#define Rd 4
#define Wd 64

typedef _Float16 h2v __attribute__((ext_vector_type(2)));

__device__ __forceinline__ float tanh_fast(float x) {
    float e = __expf(x + x);
    return 1.f - __fdividef(2.f, 1.f + e);
}

__device__ __forceinline__ float d2(unsigned a, unsigned b, float c) {
    return __builtin_amdgcn_fdot2(__builtin_bit_cast(h2v, a),
                                  __builtin_bit_cast(h2v, b), c, false);
}

__device__ __forceinline__ unsigned pk(float a, float b) {
    h2v p; p.x = (_Float16)a; p.y = (_Float16)b;
    return __builtin_bit_cast(unsigned, p);
}

// ---- build WAp = fp16-packed [W_a | lin_w^T] (256 h2 x 1024)
// ----       + Wtp (256 h2 x 512) + Wcp (256 h2 x 512) ----
__global__ __launch_bounds__(256) void k_prep(const float* __restrict__ Wa,
                                              const float* __restrict__ lin_w,
                                              const float* __restrict__ Wt,
                                              const float* __restrict__ Wc,
                                              unsigned* __restrict__ WAp,
                                              unsigned* __restrict__ Wtp,
                                              unsigned* __restrict__ Wcp) {
    __shared__ unsigned tile[32][33];
    int bx = blockIdx.x, by = blockIdx.y;
    int lane = threadIdx.x & 31, ty = threadIdx.x >> 5;
    for (int k = 0; k < 32; k += 8) {
        int h2 = by * 32 + ty + k, c = bx * 32 + lane;
        WAp[(size_t)h2 * 1024 + c] = pk(Wa[(size_t)(2 * h2) * Hd + c],
                                        Wa[(size_t)(2 * h2 + 1) * Hd + c]);
        Wtp[(size_t)h2 * 512 + c]  = pk(Wt[(size_t)(2 * h2) * Hd + c],
                                        Wt[(size_t)(2 * h2 + 1) * Hd + c]);
        Wcp[(size_t)h2 * 512 + c]  = pk(Wc[(size_t)(2 * h2) * Hd + c],
                                        Wc[(size_t)(2 * h2 + 1) * Hd + c]);
    }
    for (int k = 0; k < 32; k += 8) {
        int c_src = bx * 32 + ty + k, h2 = by * 32 + lane;
        float2 v = *(const float2*)&lin_w[(size_t)c_src * Hd + 2 * h2];
        tile[ty + k][lane] = pk(v.x, v.y);
    }
    __syncthreads();
    for (int k = 0; k < 32; k += 8) {
        int h2o = by * 32 + ty + k, co = bx * 32 + lane;
        WAp[(size_t)h2o * 1024 + 512 + co] = tile[lane][ty + k];
    }
}

// ---------------- Wctx via dot2: 256 blocks x 8 rows (k_rw pattern) ----------------
__global__ __launch_bounds__(512) void k_wctx2(const float* __restrict__ ctx_pbh,
                                               const unsigned* __restrict__ Wcp,
                                               float* __restrict__ Wctx) {
    __shared__ unsigned As[8 * 256];       // 8 rows x 256 h2, packed fp16
    int gr0 = blockIdx.x * 8, tid = threadIdx.x;
    for (int i = tid; i < 8 * 256; i += 512) {
        int rr = i >> 8, h2 = i & 255;
        int gr = gr0 + rr, b = gr >> 5, p = gr & 31;
        float2 v = *(const float2*)&ctx_pbh[((size_t)(p * Bd + b)) * Hd + (h2 << 1)];
        As[i] = pk(v.x, v.y);
    }
    __syncthreads();
    float acc[8];
    #pragma unroll
    for (int rr = 0; rr < 8; ++rr) acc[rr] = 0.f;
    const int c = tid;
    #pragma unroll 1
    for (int h2 = 0; h2 < 256; h2 += 4) {
        unsigned w0 = Wcp[((h2 + 0) << 9) + c];
        unsigned w1 = Wcp[((h2 + 1) << 9) + c];
        unsigned w2 = Wcp[((h2 + 2) << 9) + c];
        unsigned w3 = Wcp[((h2 + 3) << 9) + c];
        #pragma unroll
        for (int rr = 0; rr < 8; ++rr) {
            uint4 a4 = *(const uint4*)&As[(rr << 8) + h2];
            float s = acc[rr];
            s = d2(a4.x, w0, s); s = d2(a4.y, w1, s);
            s = d2(a4.z, w2, s); s = d2(a4.w, w3, s);
            acc[rr] = s;
        }
    }
    for (int rr = 0; rr < 8; ++rr)
        Wctx[(size_t)(gr0 + rr) * Hd + c] = acc[rr];
}

// ---------------- rwh[t*256+row][c] = fp16(sum_h resp * Wt), dot2 path ----------------
__global__ __launch_bounds__(512) void k_rw(const float* __restrict__ resp,
                                            const unsigned* __restrict__ Wtp,
                                            unsigned short* __restrict__ rwh) {
    __shared__ unsigned As[32 * 256];
    int gr0 = blockIdx.x * 32, tid = threadIdx.x;
    for (int i = tid; i < 32 * 256; i += 512) {
        int rr = i >> 8, h2 = i & 255;
        int gr = gr0 + rr;
        int t = gr >> 8, row = gr & 255, r = row >> 6, bb = row & 63;
        float2 v = *(const float2*)(resp + (((size_t)(r * Wd + t)) * Bd + bb) * Hd + (h2 << 1));
        As[i] = pk(v.x, v.y);
    }
    __syncthreads();
    float acc[32];
    #pragma unroll
    for (int rr = 0; rr < 32; ++rr) acc[rr] = 0.f;
    const int c = tid;
    #pragma unroll 1
    for (int h2 = 0; h2 < 256; h2 += 4) {
        unsigned w0 = Wtp[((h2 + 0) << 9) + c];
        unsigned w1 = Wtp[((h2 + 1) << 9) + c];
        unsigned w2 = Wtp[((h2 + 2) << 9) + c];
        unsigned w3 = Wtp[((h2 + 3) << 9) + c];
        #pragma unroll
        for (int rr = 0; rr < 32; ++rr) {
            uint4 a4 = *(const uint4*)&As[(rr << 8) + h2];
            float s = acc[rr];
            s = d2(a4.x, w0, s); s = d2(a4.y, w1, s);
            s = d2(a4.z, w2, s); s = d2(a4.w, w3, s);
            acc[rr] = s;
        }
    }
    for (int rr = 0; rr < 32; ++rr)
        rwh[((size_t)(gr0 + rr) << 9) + c] =
            __builtin_bit_cast(unsigned short, (_Float16)acc[rr]);
}

// ---- CWh[b][p2][c] = fp16-pair( ctx[p]@WA )  pairs along p (uint4 As reads) ----
__global__ __launch_bounds__(1024) void k_cw(const float* __restrict__ ctx,
                                             const unsigned* __restrict__ WAp,
                                             unsigned* __restrict__ CWh) {
    __shared__ unsigned As[8 * 256];
    const int b = blockIdx.x >> 2, oct = blockIdx.x & 3;
    const int tid = threadIdx.x;
    for (int i = tid; i < 8 * 256; i += 1024) {
        int rr = i >> 8, h2 = i & 255;
        int p = oct * 8 + rr;
        float2 v = *(const float2*)&ctx[((size_t)(p * Bd + b)) * Hd + (h2 << 1)];
        As[i] = pk(v.x, v.y);
    }
    __syncthreads();
    const int c = tid;
    float acc[8];
    #pragma unroll
    for (int rr = 0; rr < 8; ++rr) acc[rr] = 0.f;
    #pragma unroll 1
    for (int h2 = 0; h2 < 256; h2 += 4) {
        unsigned w0 = WAp[((size_t)(h2 + 0)) * 1024 + c];
        unsigned w1 = WAp[((size_t)(h2 + 1)) * 1024 + c];
        unsigned w2 = WAp[((size_t)(h2 + 2)) * 1024 + c];
        unsigned w3 = WAp[((size_t)(h2 + 3)) * 1024 + c];
        #pragma unroll
        for (int rr = 0; rr < 8; ++rr) {
            uint4 a4 = *(const uint4*)&As[(rr << 8) + h2];
            float s = acc[rr];
            s = d2(a4.x, w0, s); s = d2(a4.y, w1, s);
            s = d2(a4.z, w2, s); s = d2(a4.w, w3, s);
            acc[rr] = s;
        }
    }
    #pragma unroll
    for (int k = 0; k < 4; ++k) {
        int p2 = oct * 4 + k;
        CWh[((size_t)b * 16 + p2) * 1024 + c] = pk(acc[2 * k], acc[2 * k + 1]);
    }
}

// ---------------- persistent scan: 256 blocks (one per (r,b)), 1024 threads ----------------
// Round-13 structure with B2 removed: P2 (GEMV: tlH->sPart) and P3 (score:
// sW->scS) touch disjoint LDS and both depend only on B1 -> merged into one
// phase, 2 barriers/step. P2's loop body is verbatim (stream stays pure);
// P3 follows sequentially and overlaps P2's load drain.
__global__ __launch_bounds__(1024, 4) void k_scan(
    const float* __restrict__ ctx,      // (P,B,H)
    const unsigned short* __restrict__ rwh, // (W*256, H) fp16
    const unsigned* __restrict__ WAp,   // (H/2, 1024) half2 pairs along h
    const float* __restrict__ Wctx,     // (B*P, H)
    const float* __restrict__ walpha,   // (H)
    const float* __restrict__ hidden,   // (R,B,H)
    const float* __restrict__ lin_p,    // (H,H)
    const float* __restrict__ lin_x,    // (H,H)
    const unsigned* __restrict__ CWh,   // (B,16,1024) fp16 pairs along p
    float* __restrict__ out_resp,       // (R,B,H)
    float* __restrict__ out_alpha)      // (R,W,B,P)
{
    extern __shared__ float dynS[];
    float* sWctx  = dynS;                           // [32][512]  64 KB
    unsigned* CWs = (unsigned*)(dynS + 16384);      // [16][1024] 64 KB
    float* sPart  = dynS + 32768;                   // [4][1024]  16 KB (GEMV partials)
    float* sW     = dynS + 36864;                   // [512]       2 KB (head of w)
    float* sWal   = dynS + 37376;                   // [512]       2 KB
    float* sTl    = dynS + 37888;                   // [512]       2 KB (fp32 tl, epilogue)
    float* sAtten = dynS + 38400;                   // [512]       2 KB (epilogue)
    float* scS    = dynS + 38912;                   // [32]
    float* sAl    = dynS + 38944;                   // [32]
    unsigned* tlH = (unsigned*)(dynS + 38976);      // [256] half2 tl (16B aligned)

    const int bid = blockIdx.x;
    const int r_ = bid >> 6, b_ = bid & 63;
    const int tid = threadIdx.x;

    // ---- identities ----
    const int q  = tid >> 8;                  // P2: h2-quarter (64 h2)
    const int c4 = (tid & 255) << 2;          // P2: col quad 0..1020
    const unsigned* __restrict__ wap = WAp + ((size_t)(q << 6)) * 1024 + c4;
    const int pB = tid >> 5, hc = tid & 31;   // P3: 32 threads per p

    // ---- preamble ----
    for (int i = tid; i < 4096; i += 1024) {
        int p = i >> 7, h4 = (i & 127) << 2;
        *(float4*)&sWctx[(p << 9) + h4] =
            *(const float4*)&Wctx[((size_t)(b_ * Pd + p)) * Hd + h4];
        sPart[i] = 0.f;
    }
    for (int i = tid; i < 16384; i += 1024)
        CWs[i] = CWh[(size_t)b_ * 16384 + i];
    if (tid < Hd) sWal[tid] = walpha[tid];
    __syncthreads();

    for (int t = 0; t < Wd; ++t) {
        // ================= P1: softmax(t-1) + assemble w(t) + tanh tail =================
        {
            const int c = tid;
            unsigned short urw = 0;
            if (c < Hd)
                urw = rwh[((size_t)(t * 256 + r_ * 64 + b_) << 9) + c];
            float w = sPart[c] + sPart[1024 + c] + sPart[2048 + c] + sPart[3072 + c];
            if (t > 0) {
                float m = scS[0];
                #pragma unroll
                for (int p = 1; p < Pd; ++p) m = fmaxf(m, scS[p]);
                float e[Pd];
                float sum = 0.f;
                #pragma unroll
                for (int p = 0; p < Pd; ++p) { e[p] = __expf(scS[p] - m); sum += e[p]; }
                float inv = __fdividef(1.f, sum);
                #pragma unroll
                for (int p2 = 0; p2 < 16; ++p2)
                    w = d2(pk(e[2 * p2] * inv, e[2 * p2 + 1] * inv),
                           CWs[(p2 << 10) + c], w);
                if (tid < Pd)
                    out_alpha[(((size_t)r_ * Wd + (t - 1)) * Bd + b_) * Pd + tid] =
                        __expf(scS[tid] - m) * inv;
            }
            if (c < Hd) {
                w += (float)__builtin_bit_cast(_Float16, urw);
                sW[c] = w;
            } else {
                float tl = tanh_fast(w);
                sTl[c - Hd] = tl;
                float tn = __shfl_down(tl, 1, 64);
                if (!(c & 1)) tlH[(c - Hd) >> 1] = pk(tl, tn);
            }
        }
        __syncthreads();   // B1: sW head, tlH ready; sPart free for P2

        // ================= P2+P3 merged (disjoint LDS, both gated only by B1) =============
        // P2: PURE GEMV u(t+1) = tlH @ WA (loop body verbatim from round 13)
        if (t > 0 && t < Wd - 1) {
            float4 acc = make_float4(0.f, 0.f, 0.f, 0.f);
            #pragma unroll 4
            for (int jq = 0; jq < 16; ++jq) {
                const unsigned* wq = wap + ((size_t)jq << 12);
                uint4 w0 = *(const uint4*)(wq);
                uint4 w1 = *(const uint4*)(wq + 1024);
                uint4 w2 = *(const uint4*)(wq + 2048);
                uint4 w3 = *(const uint4*)(wq + 3072);
                uint4 a4 = *(const uint4*)&tlH[(q << 6) + (jq << 2)];
                acc.x = d2(a4.x, w0.x, acc.x); acc.y = d2(a4.x, w0.y, acc.y);
                acc.z = d2(a4.x, w0.z, acc.z); acc.w = d2(a4.x, w0.w, acc.w);
                acc.x = d2(a4.y, w1.x, acc.x); acc.y = d2(a4.y, w1.y, acc.y);
                acc.z = d2(a4.y, w1.z, acc.z); acc.w = d2(a4.y, w1.w, acc.w);
                acc.x = d2(a4.z, w2.x, acc.x); acc.y = d2(a4.z, w2.y, acc.y);
                acc.z = d2(a4.z, w2.z, acc.z); acc.w = d2(a4.z, w2.w, acc.w);
                acc.x = d2(a4.w, w3.x, acc.x); acc.y = d2(a4.w, w3.y, acc.y);
                acc.z = d2(a4.w, w3.z, acc.z); acc.w = d2(a4.w, w3.w, acc.w);
            }
            *(float4*)&sPart[(q << 10) + c4] = acc;
        }
        // P3: tanh-score -> scS (reads sW/sWctx/sWal only; overlaps P2's drain)
        {
            const float* __restrict__ wrow = sWctx + (pB << 9);
            float sc = 0.f;
            #pragma unroll
            for (int k = 0; k < 4; ++k) {
                int h4 = (k << 7) + (hc << 2);
                float4 wc = *(const float4*)&wrow[h4];
                float4 wl = *(const float4*)&sWal[h4];
                float4 v  = *(const float4*)&sW[h4];
                sc += tanh_fast(wc.x + v.x) * wl.x + tanh_fast(wc.y + v.y) * wl.y
                    + tanh_fast(wc.z + v.z) * wl.z + tanh_fast(wc.w + v.w) * wl.w;
            }
            #pragma unroll
            for (int off = 16; off; off >>= 1) sc += __shfl_down(sc, off, 32);
            if (hc == 0) scS[pB] = sc;
        }
        __syncthreads();   // B2: sPart = u(t+1) partials + scores ready for next P1
    }

    // ---- epilogue: softmax(63) -> alpha out + sAl; atten_final; output GEMM ----
    if (tid < 32) {
        float s = scS[tid];
        float m = s;
        #pragma unroll
        for (int off = 16; off; off >>= 1) m = fmaxf(m, __shfl_xor(m, off, 32));
        float e = __expf(s - m);
        float sum = e;
        #pragma unroll
        for (int off = 16; off; off >>= 1) sum += __shfl_xor(sum, off, 32);
        float al = e * __fdividef(1.f, sum);
        sAl[tid] = al;
        out_alpha[(((size_t)r_ * Wd + (Wd - 1)) * Bd + b_) * Pd + tid] = al;
    }
    __syncthreads();
    if (tid < Hd) {
        float a = sTl[tid];
        #pragma unroll 8
        for (int p = 0; p < Pd; ++p)
            a += sAl[p] * ctx[((size_t)(p * Bd + b_)) * Hd + tid];
        sAtten[tid] = a;
        sWctx[tid] = hidden[((size_t)(r_ * Bd + b_)) * Hd + tid];
    }
    __syncthreads();
    {
        const int half = tid >> 9;
        const int c = tid & 511;
        const int hb = half << 8;
        const float* __restrict__ lp = lin_p + (size_t)c * Hd + hb;
        const float* __restrict__ lx = lin_x + (size_t)c * Hd + hb;
        float f = 0.f;
        #pragma unroll 2
        for (int h = 0; h < 256; h += 4) {
            float4 lpv = *(const float4*)(lp + h);
            float4 lxv = *(const float4*)(lx + h);
            float4 aa  = *(const float4*)&sAtten[hb + h];
            float4 hh  = *(const float4*)&sWctx[hb + h];
            f += aa.x*lpv.x + aa.y*lpv.y + aa.z*lpv.z + aa.w*lpv.w
               + hh.x*lxv.x + hh.y*lxv.y + hh.z*lxv.z + hh.w*lxv.w;
        }
        sWctx[1024 + (half << 9) + c] = f;
    }
    __syncthreads();
    if (tid < Hd) {
        float f = sWctx[1024 + tid] + sWctx[1536 + tid];
        out_resp[((size_t)(r_ * Bd + b_)) * Hd + tid] = tanh_fast(f);
    }
}

extern "C" void kernel_launch(void* const* d_in, const int* in_sizes, int n_in,
                              void* d_out, int out_size, void* d_ws, size_t ws_size,
                              hipStream_t stream) {
    const float* ctx    = (const float*)d_in[0];  // (P,B,H)
    const float* resp   = (const float*)d_in[1];  // (R,W,B,H)
    const float* hidden = (const float*)d_in[2];  // (R,B,H)
    const float* Wc     = (const float*)d_in[3];
    const float* Wt     = (const float*)d_in[4];
    const float* Wa     = (const float*)d_in[5];
    const float* Walpha = (const float*)d_in[6];  // (H,1)
    const float* lin_w  = (const float*)d_in[7];
    const float* lin_p  = (const float*)d_in[8];
    const float* lin_x  = (const float*)d_in[9];

    float* out = (float*)d_out;
    float* resp_c_out = out;                       // R*B*H
    float* alpha_out  = out + Rd * Bd * Hd;        // R*W*B*P

    float* ws = (float*)d_ws;
    unsigned* WAp = (unsigned*)ws;                          //   262144 u32 (1 MB)
    unsigned* Wtp = (unsigned*)(ws + 262144);               //   131072 u32 (0.5 MB)
    unsigned* Wcp = (unsigned*)(ws + 393216);               //   131072 u32 (0.5 MB)
    float* Wctx   = ws + 524288;                            //  1048576 f32 (4 MB)
    unsigned short* rwh = (unsigned short*)(ws + 1572864);  //  8388608 u16 (16 MB)
    unsigned* CWh = (unsigned*)(ws + 5767168);              //  1048576 u32 (4 MB)
    // total ~27.3 MB

    k_prep<<<dim3(16, 8), 256, 0, stream>>>(Wa, lin_w, Wt, Wc, WAp, Wtp, Wcp);
    k_wctx2<<<256, 512, 0, stream>>>(ctx, Wcp, Wctx);
    k_rw<<<512, 512, 0, stream>>>(resp, Wtp, rwh);
    k_cw<<<256, 1024, 0, stream>>>(ctx, WAp, CWh);

    const int dyn_lds = 156928;                    // 39232 floats (~153 KB)
    static bool s_attr = false;
    if (!s_attr) {
        hipFuncSetAttribute((const void*)k_scan,
                            hipFuncAttributeMaxDynamicSharedMemorySize, dyn_lds);
        s_attr = true;
    }
    k_scan<<<256, 1024, dyn_lds, stream>>>(ctx, rwh, WAp, Wctx, Walpha, hidden,
                                           lin_p, lin_x, CWh, resp_c_out, alpha_out);
}